// Round 11
// baseline (573.334 us; speedup 1.0000x reference)
//
#include <hip/hip_runtime.h>
#include <hip/hip_bf16.h>
#include <stdint.h>

#define N_NODES 20000
#define N_EDGES 640000
#define DIM 128
#define ETPB 4            // tiles (of 128 edges) per edge block
#define EDGE_GRID (N_EDGES / (128 * ETPB))   // 1250

using bf16x8 = __attribute__((ext_vector_type(8))) short;
using f32x4  = __attribute__((ext_vector_type(4))) float;

static __device__ __forceinline__ unsigned short f2bf(float f) {
    union { float f; unsigned int u; } v; v.f = f;
    unsigned int r = v.u + 0x7FFFu + ((v.u >> 16) & 1u);
    return (unsigned short)(r >> 16);
}

// HW packed f32->bf16 (RNE): dst.lo16 = bf16(a), dst.hi16 = bf16(b). 1 VALU op.
static __device__ __forceinline__ unsigned cvt_pk_bf16(float a, float b) {
    unsigned r;
    asm("v_cvt_pk_bf16_f32 %0, %1, %2" : "=v"(r) : "v"(a), "v"(b));
    return r;
}

static __device__ __forceinline__ void glds16(const unsigned short* g, char* lds) {
    __builtin_amdgcn_global_load_lds(
        (const __attribute__((address_space(1))) unsigned int*)(const void*)g,
        (__attribute__((address_space(3))) unsigned int*)(void*)lds, 16, 0, 0);
}

// LDS write->read fence, wave-local (pins compiler order; HW LDS is in-order per wave).
static __device__ __forceinline__ void lds_fence() {
    __builtin_amdgcn_sched_barrier(0);
    asm volatile("s_waitcnt lgkmcnt(0)" ::: "memory");
    __builtin_amdgcn_sched_barrier(0);
}
// WAR pin: DS ops may not cross (VMEM/VALU/MFMA free to move).
static __device__ __forceinline__ void ds_order() {
    __builtin_amdgcn_sched_barrier(0x7F);
}

// ---------------- prep: bf16 node table, split transposed bf16 weights, zero counts ----------------
__global__ void prep_kernel(const float* __restrict__ node_feat,
                            const float* __restrict__ W1e, const float* __restrict__ W2e,
                            const float* __restrict__ W1n, const float* __restrict__ W2n,
                            unsigned short* __restrict__ node_bf,
                            unsigned short* __restrict__ Wt1ee, unsigned short* __restrict__ Wt1es,
                            unsigned short* __restrict__ Wt1ed, unsigned short* __restrict__ Wt2e,
                            unsigned short* __restrict__ Wt1n, unsigned short* __restrict__ Wt2n,
                            int* __restrict__ counts) {
    int tid = blockIdx.x * blockDim.x + threadIdx.x;
    int stride = gridDim.x * blockDim.x;
    for (int i = tid; i < N_NODES * DIM / 8; i += stride) {
        const float* p = node_feat + (size_t)i * 8;
        float4 f0 = *(const float4*)p;
        float4 f1 = *(const float4*)(p + 4);
        bf16x8 a;
        unsigned* au = (unsigned*)&a;
        au[0] = cvt_pk_bf16(f0.x, f0.y);
        au[1] = cvt_pk_bf16(f0.z, f0.w);
        au[2] = cvt_pk_bf16(f1.x, f1.y);
        au[3] = cvt_pk_bf16(f1.z, f1.w);
        *(bf16x8*)(node_bf + (size_t)i * 8) = a;
    }
    // W1e is [384][128]; rows 0:128 edge part, 128:256 src part, 256:384 dst part.
    for (int i = tid; i < DIM * DIM; i += stride) {
        int n = i >> 7, k = i & 127;
        Wt1ee[i] = f2bf(W1e[k * DIM + n]);
        Wt1es[i] = f2bf(W1e[(128 + k) * DIM + n]);
        Wt1ed[i] = f2bf(W1e[(256 + k) * DIM + n]);
        Wt2e[i]  = f2bf(W2e[k * DIM + n]);
        Wt2n[i]  = f2bf(W2n[k * DIM + n]);
    }
    for (int i = tid; i < DIM * 256; i += stride) { int n = i / 256, k = i % 256; Wt1n[i] = f2bf(W1n[k * DIM + n]); }
    for (int i = tid; i < N_NODES; i += stride) counts[i] = 0;
}

// ---------------- node projections: Ps = node @ W1e_s, Pd = node @ W1e_d (bf16 out) ----------------
__launch_bounds__(256, 1)
__global__ void proj_kernel(const unsigned short* __restrict__ node_bf,
                            const unsigned short* __restrict__ Wt1es,
                            const unsigned short* __restrict__ Wt1ed,
                            unsigned short* __restrict__ Ps,
                            unsigned short* __restrict__ Pd) {
    __shared__ char ldsWs[32768];
    __shared__ char ldsWd[32768];
    __shared__ char ldsS[4][8448];
    const int tid = threadIdx.x;
    const int wv = tid >> 6, l = tid & 63, lr = l & 15, kg = l >> 4;
    char* S = ldsS[wv];
    const int wb = blockIdx.x * 128 + wv * 32;

    int n0 = wb + lr;       if (n0 >= N_NODES) n0 = N_NODES - 1;
    int n1 = wb + 16 + lr;  if (n1 >= N_NODES) n1 = N_NODES - 1;

    bf16x8 A[4][2];
    #pragma unroll
    for (int st = 0; st < 4; ++st) {
        A[st][0] = *(const bf16x8*)(node_bf + (long)n0 * DIM + st * 32 + kg * 8);
        A[st][1] = *(const bf16x8*)(node_bf + (long)n1 * DIM + st * 32 + kg * 8);
    }

    #pragma unroll
    for (int c = 0; c < 8; ++c) {
        int Sc = c * 256 + tid;          // 0..2047
        int n = Sc >> 4, sp = Sc & 15;
        int s = (sp & 8) | ((sp ^ n) & 7);
        glds16(Wt1es + n * 128 + s * 8, ldsWs + Sc * 16);
        glds16(Wt1ed + n * 128 + s * 8, ldsWd + Sc * 16);
    }
    __syncthreads();

    #pragma unroll
    for (int T = 0; T < 2; ++T) {
        const char* W = T ? ldsWd : ldsWs;
        unsigned short* Out = T ? Pd : Ps;
        f32x4 acc[2][8];
        #pragma unroll
        for (int rt = 0; rt < 2; ++rt)
            #pragma unroll
            for (int tt = 0; tt < 8; ++tt) acc[rt][tt] = (f32x4){0.f, 0.f, 0.f, 0.f};
        #pragma unroll
        for (int s = 0; s < 4; ++s) {
            int sl = s * 4 + kg;
            int sp = (sl & 8) | ((sl ^ lr) & 7);
            #pragma unroll
            for (int tt = 0; tt < 8; ++tt) {
                bf16x8 B = *(const bf16x8*)(W + (tt * 16 + lr) * 256 + sp * 16);
                #pragma unroll
                for (int rt = 0; rt < 2; ++rt)
                    acc[rt][tt] = __builtin_amdgcn_mfma_f32_16x16x32_bf16(A[s][rt], B, acc[rt][tt], 0, 0, 0);
            }
        }
        float* sf = (float*)S;
        #pragma unroll
        for (int rt = 0; rt < 2; ++rt) {
            #pragma unroll
            for (int tt = 0; tt < 8; ++tt) {
                int col = tt * 16 + lr;
                #pragma unroll
                for (int r = 0; r < 4; ++r) {
                    int row = kg * 4 + r;
                    sf[row * 132 + (col ^ (row & 12))] = acc[rt][tt][r];
                }
            }
            lds_fence();
            #pragma unroll
            for (int rr = 0; rr < 8; ++rr) {
                int row = rr * 2 + (l >> 5);
                int c4 = (l & 31) * 4;
                float4 v = *(const float4*)(sf + row * 132 + (c4 ^ (row & 12)));
                int nrow = wb + rt * 16 + row;
                if (nrow < N_NODES) {
                    uint2 u;
                    u.x = cvt_pk_bf16(v.x, v.y);
                    u.y = cvt_pk_bf16(v.z, v.w);
                    *(uint2*)(Out + (long)nrow * DIM + c4) = u;
                }
            }
            ds_order();
        }
        __syncthreads();
    }
}

// ---------------- CSR build ----------------
__global__ void count_kernel(const int* __restrict__ eidx, int* __restrict__ counts) {
    int e = blockIdx.x * blockDim.x + threadIdx.x;
    if (e < N_EDGES) atomicAdd(&counts[eidx[N_EDGES + e]], 1);
}

__global__ void scan_kernel(const int* __restrict__ counts, int* __restrict__ offsets,
                            int* __restrict__ cursor) {
    __shared__ int wsum[16];
    const int CH = 20;
    int tid = threadIdx.x;
    int lane = tid & 63, wid = tid >> 6;
    int base = tid * CH;
    int s = 0;
    #pragma unroll
    for (int j = 0; j < CH; ++j) { int i = base + j; s += (i < N_NODES) ? counts[i] : 0; }
    int chunk = s;
    #pragma unroll
    for (int off = 1; off < 64; off <<= 1) { int t = __shfl_up(s, off, 64); if (lane >= off) s += t; }
    if (lane == 63) wsum[wid] = s;
    __syncthreads();
    if (tid == 0) {
        int run = 0;
        for (int w = 0; w < 16; ++w) { int t = wsum[w]; wsum[w] = run; run += t; }
    }
    __syncthreads();
    int run = wsum[wid] + s - chunk;
    for (int j = 0; j < CH; ++j) {
        int i = base + j;
        if (i < N_NODES) { offsets[i] = run; cursor[i] = run; run += counts[i]; }
    }
}

__global__ void scatter_kernel(const int* __restrict__ eidx, int* __restrict__ cursor,
                               int* __restrict__ elist) {
    int e = blockIdx.x * blockDim.x + threadIdx.x;
    if (e < N_EDGES) {
        int p = atomicAdd(&cursor[eidx[N_EDGES + e]], 1);
        elist[p] = e;
    }
}

// ---------------- edge MLP: K=128 coalesced GEMM + projection injection, 4-tile pipeline ----------------
// Per block: stage W1e_e + W2e once; 4 tiles of 128 edges. Register pipeline with single
// E/PJ buffers: E dies at gemm1's convert -> loadE(t+1) reissues into it; PJ dies at
// inject -> loadPJ(t+1) follows; tail(t) (~2500cy) covers both latencies. Amortizes the
// per-block prologue (eidx->gather chain + stage barrier) 4x vs R10.
__launch_bounds__(256, 2)
__global__ void edge_kernel(const float* __restrict__ edge_feat,
                            const int* __restrict__ eidx,
                            const unsigned short* __restrict__ Ps,
                            const unsigned short* __restrict__ Pd,
                            const unsigned short* __restrict__ Wt1ee,
                            const unsigned short* __restrict__ Wt2e,
                            const float* __restrict__ b1e,
                            const float* __restrict__ b2e,
                            float* __restrict__ out_edge) {
    __shared__ char ldsW1[32768];
    __shared__ char ldsW2[32768];
    __shared__ char ldsS[4][4096];
    const int tid = threadIdx.x;
    const int wv = tid >> 6, l = tid & 63, lr = l & 15, kg = l >> 4;
    char* S = ldsS[wv];
    const int blkBase = blockIdx.x * (128 * ETPB);

    float4 E[4][2][2];
    bf16x8 PJ[2][8];

    auto loadE = [&](int t) {
        int tb = blkBase + t * 128 + wv * 32;
        int e0 = tb + lr, e1 = tb + 16 + lr;
        #pragma unroll
        for (int st = 0; st < 4; ++st) {
            const float* p0 = edge_feat + (long)e0 * DIM + st * 32 + kg * 8;
            const float* p1 = edge_feat + (long)e1 * DIM + st * 32 + kg * 8;
            E[st][0][0] = *(const float4*)p0; E[st][0][1] = *(const float4*)(p0 + 4);
            E[st][1][0] = *(const float4*)p1; E[st][1][1] = *(const float4*)(p1 + 4);
        }
    };
    auto loadPJ = [&](int t) {
        int tb = blkBase + t * 128 + wv * 32;
        int e0 = tb + lr, e1 = tb + 16 + lr;
        int s0 = eidx[e0], d0 = eidx[N_EDGES + e0];
        int s1 = eidx[e1], d1 = eidx[N_EDGES + e1];
        const unsigned short* Tbl = (kg < 2) ? Ps : Pd;
        const long r0 = (long)((kg < 2) ? s0 : d0) * DIM;
        const long r1 = (long)((kg < 2) ? s1 : d1) * DIM;
        const int ko = (kg & 1) * 8;
        #pragma unroll
        for (int tt = 0; tt < 8; ++tt) {
            PJ[0][tt] = *(const bf16x8*)(Tbl + r0 + tt * 16 + ko);
            PJ[1][tt] = *(const bf16x8*)(Tbl + r1 + tt * 16 + ko);
        }
    };

    float b1r[8], b2r[8];
    #pragma unroll
    for (int tt = 0; tt < 8; ++tt) { b1r[tt] = b1e[tt * 16 + lr]; b2r[tt] = b2e[tt * 16 + lr]; }

    // ---- tile-0 loads, then weight staging (barrier drains everything) ----
    loadE(0);
    loadPJ(0);
    #pragma unroll
    for (int c = 0; c < 8; ++c) {
        int Sc = c * 256 + tid;
        int n = Sc >> 4, sp = Sc & 15;
        int s = (sp & 8) | ((sp ^ n) & 7);
        glds16(Wt1ee + n * 128 + s * 8, ldsW1 + Sc * 16);
        glds16(Wt2e + n * 128 + s * 8, ldsW2 + Sc * 16);
    }
    __syncthreads();

    // ---- one-hot B fragment for the injection MFMA ----
    bf16x8 bid;
    #pragma unroll
    for (int j = 0; j < 8; ++j) {
        int k = kg * 8 + j;
        int kk = (k < 16) ? k : k - 16;
        bid[j] = (short)((kk == lr) ? 0x3F80 : 0);
    }

    #pragma unroll
    for (int t = 0; t < ETPB; ++t) {
        const int tb = blkBase + t * 128 + wv * 32;

        // ---- GEMM1: K=128 over edge_feat (converted inline; consumes E) ----
        f32x4 acc[2][8];
        #pragma unroll
        for (int rt = 0; rt < 2; ++rt)
            #pragma unroll
            for (int tt = 0; tt < 8; ++tt) acc[rt][tt] = (f32x4){0.f, 0.f, 0.f, 0.f};

        #pragma unroll
        for (int s = 0; s < 4; ++s) {
            bf16x8 EB[2];
            #pragma unroll
            for (int rt = 0; rt < 2; ++rt) {
                bf16x8 a;
                unsigned* au = (unsigned*)&a;
                au[0] = cvt_pk_bf16(E[s][rt][0].x, E[s][rt][0].y);
                au[1] = cvt_pk_bf16(E[s][rt][0].z, E[s][rt][0].w);
                au[2] = cvt_pk_bf16(E[s][rt][1].x, E[s][rt][1].y);
                au[3] = cvt_pk_bf16(E[s][rt][1].z, E[s][rt][1].w);
                EB[rt] = a;
            }
            int sl = s * 4 + kg;
            int sp = (sl & 8) | ((sl ^ lr) & 7);
            #pragma unroll
            for (int tt = 0; tt < 8; ++tt) {
                bf16x8 B = *(const bf16x8*)(ldsW1 + (tt * 16 + lr) * 256 + sp * 16);
                #pragma unroll
                for (int rt = 0; rt < 2; ++rt)
                    acc[rt][tt] = __builtin_amdgcn_mfma_f32_16x16x32_bf16(EB[rt], B, acc[rt][tt], 0, 0, 0);
            }
        }
        if (t + 1 < ETPB) loadE(t + 1);        // E regs free -> prefetch next tile

        // ---- inject Ps[src] + Pd[dst] (consumes PJ) ----
        #pragma unroll
        for (int tt = 0; tt < 8; ++tt)
            #pragma unroll
            for (int rt = 0; rt < 2; ++rt)
                acc[rt][tt] = __builtin_amdgcn_mfma_f32_16x16x32_bf16(PJ[rt][tt], bid, acc[rt][tt], 0, 0, 0);
        if (t + 1 < ETPB) loadPJ(t + 1);       // PJ regs free -> prefetch next tile

        // ---- GEMM2 through fenced wave-private h chunks (cvt_pk + hi extract) ----
        f32x4 acc2[2][8];
        #pragma unroll
        for (int rt = 0; rt < 2; ++rt)
            #pragma unroll
            for (int tt = 0; tt < 8; ++tt) acc2[rt][tt] = (f32x4){0.f, 0.f, 0.f, 0.f};

        #pragma unroll
        for (int q = 0; q < 4; ++q) {
            #pragma unroll
            for (int rt = 0; rt < 2; ++rt)
                #pragma unroll
                for (int t2 = 0; t2 < 2; ++t2) {
                    int tt = q * 2 + t2;
                    int slot = t2 * 2 + (lr >> 3);
                    #pragma unroll
                    for (int r = 0; r < 4; r += 2) {
                        int row0 = rt * 16 + kg * 4 + r;
                        float x0 = acc[rt][tt][r] + b1r[tt];
                        float x1 = acc[rt][tt][r + 1] + b1r[tt];
                        float h0 = x0 / (1.0f + __expf(-x0));
                        float h1 = x1 / (1.0f + __expf(-x1));
                        unsigned p = cvt_pk_bf16(h0, h1);
                        int byte0 = row0 * 64 + ((slot ^ ((row0 >> 1) & 3)) << 4) + (lr & 7) * 2;
                        *(unsigned short*)(S + byte0) = (unsigned short)p;
                        *(unsigned short*)(S + byte0 + 64) = (unsigned short)(p >> 16);
                    }
                }
            lds_fence();
            bf16x8 A2[2];
            #pragma unroll
            for (int rt = 0; rt < 2; ++rt) {
                int row = rt * 16 + lr;
                int byte = row * 64 + ((kg ^ ((row >> 1) & 3)) << 4);
                A2[rt] = *(const bf16x8*)(S + byte);
            }
            ds_order();
            int sl2 = q * 4 + kg;
            int sp2 = (sl2 & 8) | ((sl2 ^ lr) & 7);
            #pragma unroll
            for (int tt = 0; tt < 8; ++tt) {
                bf16x8 B = *(const bf16x8*)(ldsW2 + (tt * 16 + lr) * 256 + sp2 * 16);
                #pragma unroll
                for (int rt = 0; rt < 2; ++rt)
                    acc2[rt][tt] = __builtin_amdgcn_mfma_f32_16x16x32_bf16(A2[rt], B, acc2[rt][tt], 0, 0, 0);
            }
        }

        // ---- epilogue: fenced f32 strips; residual loads batched per strip (L2-hot) ----
        #pragma unroll
        for (int rt = 0; rt < 2; ++rt)
            #pragma unroll
            for (int ch = 0; ch < 2; ++ch) {
                float4 rs4[4];
                #pragma unroll
                for (int i = 0; i < 4; ++i) {
                    int row = (l >> 4) + i * 4;
                    int slot = l & 15;
                    long gidx = (long)(tb + rt * 16 + row) * DIM + ch * 64 + slot * 4;
                    rs4[i] = *(const float4*)(edge_feat + gidx);
                }
                #pragma unroll
                for (int t2 = 0; t2 < 4; ++t2) {
                    int tt = ch * 4 + t2;
                    #pragma unroll
                    for (int r = 0; r < 4; ++r) {
                        int row = kg * 4 + r;
                        int col = t2 * 16 + lr;
                        int byte = row * 256 + (((col >> 2) ^ (row & 15)) << 4) + (col & 3) * 4;
                        *(float*)(S + byte) = acc2[rt][tt][r] + b2r[tt];
                    }
                }
                lds_fence();
                #pragma unroll
                for (int i = 0; i < 4; ++i) {
                    int row = (l >> 4) + i * 4;
                    int slot = l & 15;
                    int byte = row * 256 + ((slot ^ (row & 15)) << 4);
                    float4 v = *(const float4*)(S + byte);
                    long gidx = (long)(tb + rt * 16 + row) * DIM + ch * 64 + slot * 4;
                    v.x += rs4[i].x; v.y += rs4[i].y; v.z += rs4[i].z; v.w += rs4[i].w;
                    *(float4*)(out_edge + gidx) = v;
                }
                ds_order();
            }
    }
}

// ---------------- mean aggregation: 1 node per block, 4 waves (one 8-deep burst each) ----------------
__global__ void agg_kernel(const float* __restrict__ edge_out,
                           const int* __restrict__ offsets, const int* __restrict__ counts,
                           const int* __restrict__ elist,
                           unsigned short* __restrict__ agg_bf) {
    __shared__ float part[4][128];
    int wv = threadIdx.x >> 6;
    int l = threadIdx.x & 63;
    int n = blockIdx.x;
    int off = offsets[n], cnt = counts[n];
    int beg = (cnt * wv) >> 2;
    int end = (cnt * (wv + 1)) >> 2;
    float a0 = 0.f, a1 = 0.f;
    int i = beg;
    for (; i + 8 <= end; i += 8) {
        int ee[8];
        #pragma unroll
        for (int j = 0; j < 8; ++j) ee[j] = elist[off + i + j];
        float2 vv[8];
        #pragma unroll
        for (int j = 0; j < 8; ++j) vv[j] = *(const float2*)(edge_out + (long)ee[j] * DIM + l * 2);
        #pragma unroll
        for (int j = 0; j < 8; ++j) { a0 += vv[j].x; a1 += vv[j].y; }
    }
    for (; i < end; ++i) {
        int e = elist[off + i];
        float2 v = *(const float2*)(edge_out + (long)e * DIM + l * 2);
        a0 += v.x; a1 += v.y;
    }
    part[wv][l * 2] = a0;
    part[wv][l * 2 + 1] = a1;
    __syncthreads();
    if (wv == 0) {
        a0 = part[0][l * 2] + part[1][l * 2] + part[2][l * 2] + part[3][l * 2];
        a1 = part[0][l * 2 + 1] + part[1][l * 2 + 1] + part[2][l * 2 + 1] + part[3][l * 2 + 1];
        float inv = 1.0f / fmaxf((float)cnt, 1.0f);
        *(unsigned*)(agg_bf + (long)n * DIM + l * 2) = cvt_pk_bf16(a0 * inv, a1 * inv);
    }
}

// ---------------- node MLP ----------------
#define SLICE_B 8448
__launch_bounds__(256, 4)
__global__ void node_kernel(const float* __restrict__ node_feat,
                            const unsigned short* __restrict__ node_bf,
                            const unsigned short* __restrict__ agg_bf,
                            const unsigned short* __restrict__ Wt1n,
                            const unsigned short* __restrict__ Wt2n,
                            const float* __restrict__ b1n,
                            const float* __restrict__ b2n,
                            float* __restrict__ out_node) {
    __shared__ char lds[4][SLICE_B];
    const int tid = threadIdx.x;
    const int wv = tid >> 6;
    const int l = tid & 63;
    const int lr = l & 15;
    const int kg = l >> 4;
    char* slice = lds[wv];

    const int nBase = blockIdx.x * 128;
    const int wBase = nBase + wv * 32;

    int rowc[2];
    #pragma unroll
    for (int rt = 0; rt < 2; ++rt) {
        int row = wBase + rt * 16 + lr;
        rowc[rt] = row < N_NODES ? row : N_NODES - 1;
    }

    f32x4 acc[2][8];
    #pragma unroll
    for (int rt = 0; rt < 2; ++rt)
        #pragma unroll
        for (int t = 0; t < 8; ++t) acc[rt][t] = (f32x4){0.f, 0.f, 0.f, 0.f};

    #pragma unroll
    for (int s = 0; s < 8; ++s) {
        const int kk = s * 32 + kg * 8;
        bf16x8 A[2];
        if (s < 4) {
            #pragma unroll
            for (int rt = 0; rt < 2; ++rt)
                A[rt] = *(const bf16x8*)(node_bf + (long)rowc[rt] * DIM + kk);
        } else {
            #pragma unroll
            for (int rt = 0; rt < 2; ++rt)
                A[rt] = *(const bf16x8*)(agg_bf + (long)rowc[rt] * DIM + (kk - 128));
        }
        #pragma unroll
        for (int t = 0; t < 8; ++t) {
            bf16x8 B = *(const bf16x8*)(Wt1n + (t * 16 + lr) * 256 + kk);
            #pragma unroll
            for (int rt = 0; rt < 2; ++rt)
                acc[rt][t] = __builtin_amdgcn_mfma_f32_16x16x32_bf16(A[rt], B, acc[rt][t], 0, 0, 0);
        }
    }

    #pragma unroll
    for (int rt = 0; rt < 2; ++rt) {
        #pragma unroll
        for (int t = 0; t < 8; ++t) {
            float b1 = b1n[t * 16 + lr];
            int col = t * 16 + lr;
            #pragma unroll
            for (int r = 0; r < 4; ++r) {
                int row = rt * 16 + kg * 4 + r;
                float x = acc[rt][t][r] + b1;
                float h = x / (1.0f + __expf(-x));
                int byte = (row * 256 + col * 2) ^ ((row & 7) << 4);
                *(unsigned short*)(slice + byte) = f2bf(h);
            }
        }
    }
    __syncthreads();

    f32x4 acc2[2][8];
    #pragma unroll
    for (int rt = 0; rt < 2; ++rt)
        #pragma unroll
        for (int t = 0; t < 8; ++t) acc2[rt][t] = (f32x4){0.f, 0.f, 0.f, 0.f};

    #pragma unroll
    for (int s = 0; s < 4; ++s) {
        const int kk = s * 32 + kg * 8;
        bf16x8 A[2];
        #pragma unroll
        for (int rt = 0; rt < 2; ++rt) {
            int row = rt * 16 + lr;
            int byte = (row * 256 + kk * 2) ^ ((row & 7) << 4);
            A[rt] = *(const bf16x8*)(slice + byte);
        }
        #pragma unroll
        for (int t = 0; t < 8; ++t) {
            bf16x8 B = *(const bf16x8*)(Wt2n + (t * 16 + lr) * DIM + kk);
            #pragma unroll
            for (int rt = 0; rt < 2; ++rt)
                acc2[rt][t] = __builtin_amdgcn_mfma_f32_16x16x32_bf16(A[rt], B, acc2[rt][t], 0, 0, 0);
        }
    }
    __syncthreads();

    #pragma unroll
    for (int rt = 0; rt < 2; ++rt) {
        float* sf = (float*)slice;
        #pragma unroll
        for (int t = 0; t < 8; ++t) {
            float b2 = b2n[t * 16 + lr];
            int col = t * 16 + lr;
            #pragma unroll
            for (int r = 0; r < 4; ++r) {
                int row = kg * 4 + r;
                int colp = col ^ (row & 12);
                sf[row * 132 + colp] = acc2[rt][t][r] + b2;
            }
        }
        __syncthreads();
        #pragma unroll
        for (int rr = 0; rr < 8; ++rr) {
            int row = rr * 2 + (l >> 5);
            int c4 = (l & 31) * 4;
            int cswz = c4 ^ (row & 12);
            float4 v = *(const float4*)(sf + row * 132 + cswz);
            int grow = wBase + rt * 16 + row;
            if (grow < N_NODES) {
                long gidx = (long)grow * DIM + c4;
                float4 rsd = *(const float4*)(node_feat + gidx);
                v.x += rsd.x; v.y += rsd.y; v.z += rsd.z; v.w += rsd.w;
                *(float4*)(out_node + gidx) = v;
            }
        }
        __syncthreads();
    }
}

extern "C" void kernel_launch(void* const* d_in, const int* in_sizes, int n_in,
                              void* d_out, int out_size, void* d_ws, size_t ws_size,
                              hipStream_t stream) {
    const float* node_feat = (const float*)d_in[0];
    const float* edge_feat = (const float*)d_in[1];
    const int*   eidx      = (const int*)d_in[2];
    const float* W1e = (const float*)d_in[3];
    const float* b1e = (const float*)d_in[4];
    const float* W2e = (const float*)d_in[5];
    const float* b2e = (const float*)d_in[6];
    const float* W1n = (const float*)d_in[7];
    const float* b1n = (const float*)d_in[8];
    const float* W2n = (const float*)d_in[9];
    const float* b2n = (const float*)d_in[10];

    char* ws = (char*)d_ws;
    size_t off = 0;
    auto alloc = [&](size_t bytes) {
        void* p = ws + off;
        off += (bytes + 255) & ~(size_t)255;
        return p;
    };
    unsigned short* node_bf = (unsigned short*)alloc((size_t)N_NODES * DIM * 2);
    unsigned short* agg_bf  = (unsigned short*)alloc((size_t)N_NODES * DIM * 2);
    unsigned short* Ps      = (unsigned short*)alloc((size_t)N_NODES * DIM * 2);
    unsigned short* Pd      = (unsigned short*)alloc((size_t)N_NODES * DIM * 2);
    unsigned short* Wt1ee   = (unsigned short*)alloc((size_t)DIM * DIM * 2);
    unsigned short* Wt1es   = (unsigned short*)alloc((size_t)DIM * DIM * 2);
    unsigned short* Wt1ed   = (unsigned short*)alloc((size_t)DIM * DIM * 2);
    unsigned short* Wt2e    = (unsigned short*)alloc((size_t)DIM * DIM * 2);
    unsigned short* Wt1n    = (unsigned short*)alloc((size_t)DIM * 256 * 2);
    unsigned short* Wt2n    = (unsigned short*)alloc((size_t)DIM * DIM * 2);
    int* counts  = (int*)alloc((size_t)N_NODES * 4);
    int* offsets = (int*)alloc((size_t)N_NODES * 4);
    int* cursor  = (int*)alloc((size_t)N_NODES * 4);
    int* elist   = (int*)alloc((size_t)N_EDGES * 4);

    float* out_node = (float*)d_out;
    float* out_edge = out_node + (size_t)N_NODES * DIM;

    prep_kernel<<<512, 256, 0, stream>>>(node_feat, W1e, W2e, W1n, W2n, node_bf,
                                         Wt1ee, Wt1es, Wt1ed, Wt2e, Wt1n, Wt2n, counts);
    proj_kernel<<<(N_NODES + 127) / 128, 256, 0, stream>>>(node_bf, Wt1es, Wt1ed, Ps, Pd);
    count_kernel<<<(N_EDGES + 255) / 256, 256, 0, stream>>>(eidx, counts);
    scan_kernel<<<1, 1024, 0, stream>>>(counts, offsets, cursor);
    scatter_kernel<<<(N_EDGES + 255) / 256, 256, 0, stream>>>(eidx, cursor, elist);
    edge_kernel<<<EDGE_GRID, 256, 0, stream>>>(edge_feat, eidx, Ps, Pd, Wt1ee, Wt2e,
                                               b1e, b2e, out_edge);
    agg_kernel<<<N_NODES, 256, 0, stream>>>(out_edge, offsets, counts, elist, agg_bf);
    node_kernel<<<(N_NODES + 127) / 128, 256, 0, stream>>>(node_feat, node_bf, agg_bf,
                                                           Wt1n, Wt2n, b1n, b2n, out_node);
}

// Round 12
// 567.682 us; speedup vs baseline: 1.0100x; 1.0100x over previous
//
#include <hip/hip_runtime.h>
#include <hip/hip_bf16.h>
#include <stdint.h>

#define N_NODES 20000
#define N_EDGES 640000
#define DIM 128

using bf16x8 = __attribute__((ext_vector_type(8))) short;
using f32x4  = __attribute__((ext_vector_type(4))) float;

static __device__ __forceinline__ unsigned short f2bf(float f) {
    union { float f; unsigned int u; } v; v.f = f;
    unsigned int r = v.u + 0x7FFFu + ((v.u >> 16) & 1u);
    return (unsigned short)(r >> 16);
}

// HW packed f32->bf16 (RNE): dst.lo16 = bf16(a), dst.hi16 = bf16(b). 1 VALU op.
static __device__ __forceinline__ unsigned cvt_pk_bf16(float a, float b) {
    unsigned r;
    asm("v_cvt_pk_bf16_f32 %0, %1, %2" : "=v"(r) : "v"(a), "v"(b));
    return r;
}

static __device__ __forceinline__ void glds16(const unsigned short* g, char* lds) {
    __builtin_amdgcn_global_load_lds(
        (const __attribute__((address_space(1))) unsigned int*)(const void*)g,
        (__attribute__((address_space(3))) unsigned int*)(void*)lds, 16, 0, 0);
}

// LDS write->read fence, wave-local (pins compiler order; HW LDS is in-order per wave).
static __device__ __forceinline__ void lds_fence() {
    __builtin_amdgcn_sched_barrier(0);
    asm volatile("s_waitcnt lgkmcnt(0)" ::: "memory");
    __builtin_amdgcn_sched_barrier(0);
}
// WAR pin: DS ops may not cross (VMEM/VALU/MFMA free to move).
static __device__ __forceinline__ void ds_order() {
    __builtin_amdgcn_sched_barrier(0x7F);
}

// ---------------- prep: bf16 node table, split transposed bf16 weights, zero counts ----------------
__global__ void prep_kernel(const float* __restrict__ node_feat,
                            const float* __restrict__ W1e, const float* __restrict__ W2e,
                            const float* __restrict__ W1n, const float* __restrict__ W2n,
                            unsigned short* __restrict__ node_bf,
                            unsigned short* __restrict__ Wt1ee, unsigned short* __restrict__ Wt1es,
                            unsigned short* __restrict__ Wt1ed, unsigned short* __restrict__ Wt2e,
                            unsigned short* __restrict__ Wt1n, unsigned short* __restrict__ Wt2n,
                            int* __restrict__ counts) {
    int tid = blockIdx.x * blockDim.x + threadIdx.x;
    int stride = gridDim.x * blockDim.x;
    for (int i = tid; i < N_NODES * DIM / 8; i += stride) {
        const float* p = node_feat + (size_t)i * 8;
        float4 f0 = *(const float4*)p;
        float4 f1 = *(const float4*)(p + 4);
        bf16x8 a;
        unsigned* au = (unsigned*)&a;
        au[0] = cvt_pk_bf16(f0.x, f0.y);
        au[1] = cvt_pk_bf16(f0.z, f0.w);
        au[2] = cvt_pk_bf16(f1.x, f1.y);
        au[3] = cvt_pk_bf16(f1.z, f1.w);
        *(bf16x8*)(node_bf + (size_t)i * 8) = a;
    }
    // W1e is [384][128]; rows 0:128 edge part, 128:256 src part, 256:384 dst part.
    for (int i = tid; i < DIM * DIM; i += stride) {
        int n = i >> 7, k = i & 127;
        Wt1ee[i] = f2bf(W1e[k * DIM + n]);
        Wt1es[i] = f2bf(W1e[(128 + k) * DIM + n]);
        Wt1ed[i] = f2bf(W1e[(256 + k) * DIM + n]);
        Wt2e[i]  = f2bf(W2e[k * DIM + n]);
        Wt2n[i]  = f2bf(W2n[k * DIM + n]);
    }
    for (int i = tid; i < DIM * 256; i += stride) { int n = i / 256, k = i % 256; Wt1n[i] = f2bf(W1n[k * DIM + n]); }
    for (int i = tid; i < N_NODES; i += stride) counts[i] = 0;
}

// ---------------- node projections: Ps = node @ W1e_s, Pd = node @ W1e_d (bf16 out) ----------------
__launch_bounds__(256, 1)
__global__ void proj_kernel(const unsigned short* __restrict__ node_bf,
                            const unsigned short* __restrict__ Wt1es,
                            const unsigned short* __restrict__ Wt1ed,
                            unsigned short* __restrict__ Ps,
                            unsigned short* __restrict__ Pd) {
    __shared__ char ldsWs[32768];
    __shared__ char ldsWd[32768];
    __shared__ char ldsS[4][8448];
    const int tid = threadIdx.x;
    const int wv = tid >> 6, l = tid & 63, lr = l & 15, kg = l >> 4;
    char* S = ldsS[wv];
    const int wb = blockIdx.x * 128 + wv * 32;

    int n0 = wb + lr;       if (n0 >= N_NODES) n0 = N_NODES - 1;
    int n1 = wb + 16 + lr;  if (n1 >= N_NODES) n1 = N_NODES - 1;

    bf16x8 A[4][2];
    #pragma unroll
    for (int st = 0; st < 4; ++st) {
        A[st][0] = *(const bf16x8*)(node_bf + (long)n0 * DIM + st * 32 + kg * 8);
        A[st][1] = *(const bf16x8*)(node_bf + (long)n1 * DIM + st * 32 + kg * 8);
    }

    #pragma unroll
    for (int c = 0; c < 8; ++c) {
        int Sc = c * 256 + tid;          // 0..2047
        int n = Sc >> 4, sp = Sc & 15;
        int s = (sp & 8) | ((sp ^ n) & 7);
        glds16(Wt1es + n * 128 + s * 8, ldsWs + Sc * 16);
        glds16(Wt1ed + n * 128 + s * 8, ldsWd + Sc * 16);
    }
    __syncthreads();

    #pragma unroll
    for (int T = 0; T < 2; ++T) {
        const char* W = T ? ldsWd : ldsWs;
        unsigned short* Out = T ? Pd : Ps;
        f32x4 acc[2][8];
        #pragma unroll
        for (int rt = 0; rt < 2; ++rt)
            #pragma unroll
            for (int tt = 0; tt < 8; ++tt) acc[rt][tt] = (f32x4){0.f, 0.f, 0.f, 0.f};
        #pragma unroll
        for (int s = 0; s < 4; ++s) {
            int sl = s * 4 + kg;
            int sp = (sl & 8) | ((sl ^ lr) & 7);
            #pragma unroll
            for (int tt = 0; tt < 8; ++tt) {
                bf16x8 B = *(const bf16x8*)(W + (tt * 16 + lr) * 256 + sp * 16);
                #pragma unroll
                for (int rt = 0; rt < 2; ++rt)
                    acc[rt][tt] = __builtin_amdgcn_mfma_f32_16x16x32_bf16(A[s][rt], B, acc[rt][tt], 0, 0, 0);
            }
        }
        float* sf = (float*)S;
        #pragma unroll
        for (int rt = 0; rt < 2; ++rt) {
            #pragma unroll
            for (int tt = 0; tt < 8; ++tt) {
                int col = tt * 16 + lr;
                #pragma unroll
                for (int r = 0; r < 4; ++r) {
                    int row = kg * 4 + r;
                    sf[row * 132 + (col ^ (row & 12))] = acc[rt][tt][r];
                }
            }
            lds_fence();
            #pragma unroll
            for (int rr = 0; rr < 8; ++rr) {
                int row = rr * 2 + (l >> 5);
                int c4 = (l & 31) * 4;
                float4 v = *(const float4*)(sf + row * 132 + (c4 ^ (row & 12)));
                int nrow = wb + rt * 16 + row;
                if (nrow < N_NODES) {
                    uint2 u;
                    u.x = cvt_pk_bf16(v.x, v.y);
                    u.y = cvt_pk_bf16(v.z, v.w);
                    *(uint2*)(Out + (long)nrow * DIM + c4) = u;
                }
            }
            ds_order();
        }
        __syncthreads();
    }
}

// ---------------- CSR build ----------------
__global__ void count_kernel(const int* __restrict__ eidx, int* __restrict__ counts) {
    int e = blockIdx.x * blockDim.x + threadIdx.x;
    if (e < N_EDGES) atomicAdd(&counts[eidx[N_EDGES + e]], 1);
}

__global__ void scan_kernel(const int* __restrict__ counts, int* __restrict__ offsets,
                            int* __restrict__ cursor) {
    __shared__ int wsum[16];
    const int CH = 20;
    int tid = threadIdx.x;
    int lane = tid & 63, wid = tid >> 6;
    int base = tid * CH;
    int s = 0;
    #pragma unroll
    for (int j = 0; j < CH; ++j) { int i = base + j; s += (i < N_NODES) ? counts[i] : 0; }
    int chunk = s;
    #pragma unroll
    for (int off = 1; off < 64; off <<= 1) { int t = __shfl_up(s, off, 64); if (lane >= off) s += t; }
    if (lane == 63) wsum[wid] = s;
    __syncthreads();
    if (tid == 0) {
        int run = 0;
        for (int w = 0; w < 16; ++w) { int t = wsum[w]; wsum[w] = run; run += t; }
    }
    __syncthreads();
    int run = wsum[wid] + s - chunk;
    for (int j = 0; j < CH; ++j) {
        int i = base + j;
        if (i < N_NODES) { offsets[i] = run; cursor[i] = run; run += counts[i]; }
    }
}

__global__ void scatter_kernel(const int* __restrict__ eidx, int* __restrict__ cursor,
                               int* __restrict__ elist) {
    int e = blockIdx.x * blockDim.x + threadIdx.x;
    if (e < N_EDGES) {
        int p = atomicAdd(&cursor[eidx[N_EDGES + e]], 1);
        elist[p] = e;
    }
}

// ---------------- edge MLP: K=128 coalesced GEMM + projection injection ----------------
// R10 structure (the 124-VGPR config the allocator likes), one change: W2e's B-fragments
// are streamed from global (32 KB, L2-resident; ~640 MB L2 traffic << 34.5 TB/s ceiling)
// instead of LDS. LDS drops 80->48 KB => 3 blocks/CU = 3 waves/SIMD (+50% TLP to cover
// gather/fence/L2 latencies). launch_bounds(256,3) caps VGPR at 168 >= ~124 needed.
__launch_bounds__(256, 3)
__global__ void edge_kernel(const float* __restrict__ edge_feat,
                            const int* __restrict__ eidx,
                            const unsigned short* __restrict__ Ps,
                            const unsigned short* __restrict__ Pd,
                            const unsigned short* __restrict__ Wt1ee,
                            const unsigned short* __restrict__ Wt2e,
                            const float* __restrict__ b1e,
                            const float* __restrict__ b2e,
                            float* __restrict__ out_edge) {
    __shared__ char ldsW1[32768];
    __shared__ char ldsS[4][4096];
    const int tid = threadIdx.x;
    const int wv = tid >> 6, l = tid & 63, lr = l & 15, kg = l >> 4;
    char* S = ldsS[wv];
    const int tb = blockIdx.x * 128 + wv * 32;

    const int e0 = tb + lr, e1 = tb + 16 + lr;
    const int s0 = eidx[e0], d0 = eidx[N_EDGES + e0];
    const int s1 = eidx[e1], d1 = eidx[N_EDGES + e1];

    // ---- issue edge stream loads first (coalesced, also warms L2 for residual) ----
    float4 E[4][2][2];
    #pragma unroll
    for (int st = 0; st < 4; ++st) {
        const float* p0 = edge_feat + (long)e0 * DIM + st * 32 + kg * 8;
        const float* p1 = edge_feat + (long)e1 * DIM + st * 32 + kg * 8;
        E[st][0][0] = *(const float4*)p0; E[st][0][1] = *(const float4*)(p0 + 4);
        E[st][1][0] = *(const float4*)p1; E[st][1][1] = *(const float4*)(p1 + 4);
    }

    // ---- projection gathers in injection-A layout: kg<2 -> Ps[src], kg>=2 -> Pd[dst] ----
    const unsigned short* Tbl = (kg < 2) ? Ps : Pd;
    const long r0 = (long)((kg < 2) ? s0 : d0) * DIM;
    const long r1 = (long)((kg < 2) ? s1 : d1) * DIM;
    const int ko = (kg & 1) * 8;
    bf16x8 PJ[2][8];
    #pragma unroll
    for (int tt = 0; tt < 8; ++tt) {
        PJ[0][tt] = *(const bf16x8*)(Tbl + r0 + tt * 16 + ko);
        PJ[1][tt] = *(const bf16x8*)(Tbl + r1 + tt * 16 + ko);
    }

    float b1r[8], b2r[8];
    #pragma unroll
    for (int tt = 0; tt < 8; ++tt) { b1r[tt] = b1e[tt * 16 + lr]; b2r[tt] = b2e[tt * 16 + lr]; }

    // ---- stage W1e_e once (linear dest, pre-swizzled source) ----
    #pragma unroll
    for (int c = 0; c < 8; ++c) {
        int Sc = c * 256 + tid;          // 0..2047
        int n = Sc >> 4, sp = Sc & 15;
        int s = (sp & 8) | ((sp ^ n) & 7);
        glds16(Wt1ee + n * 128 + s * 8, ldsW1 + Sc * 16);
    }
    __syncthreads();

    // ---- one-hot B fragment for the injection MFMA ----
    bf16x8 bid;
    #pragma unroll
    for (int j = 0; j < 8; ++j) {
        int k = kg * 8 + j;
        int kk = (k < 16) ? k : k - 16;
        bid[j] = (short)((kk == lr) ? 0x3F80 : 0);
    }

    // ---- GEMM1: K=128 over edge_feat (converted inline via cvt_pk) ----
    f32x4 acc[2][8];
    #pragma unroll
    for (int rt = 0; rt < 2; ++rt)
        #pragma unroll
        for (int tt = 0; tt < 8; ++tt) acc[rt][tt] = (f32x4){0.f, 0.f, 0.f, 0.f};

    #pragma unroll
    for (int s = 0; s < 4; ++s) {
        bf16x8 EB[2];
        #pragma unroll
        for (int rt = 0; rt < 2; ++rt) {
            bf16x8 a;
            unsigned* au = (unsigned*)&a;
            au[0] = cvt_pk_bf16(E[s][rt][0].x, E[s][rt][0].y);
            au[1] = cvt_pk_bf16(E[s][rt][0].z, E[s][rt][0].w);
            au[2] = cvt_pk_bf16(E[s][rt][1].x, E[s][rt][1].y);
            au[3] = cvt_pk_bf16(E[s][rt][1].z, E[s][rt][1].w);
            EB[rt] = a;
        }
        int sl = s * 4 + kg;
        int sp = (sl & 8) | ((sl ^ lr) & 7);
        #pragma unroll
        for (int tt = 0; tt < 8; ++tt) {
            bf16x8 B = *(const bf16x8*)(ldsW1 + (tt * 16 + lr) * 256 + sp * 16);
            #pragma unroll
            for (int rt = 0; rt < 2; ++rt)
                acc[rt][tt] = __builtin_amdgcn_mfma_f32_16x16x32_bf16(EB[rt], B, acc[rt][tt], 0, 0, 0);
        }
    }
    // ---- inject Ps[src] + Pd[dst] ----
    #pragma unroll
    for (int tt = 0; tt < 8; ++tt)
        #pragma unroll
        for (int rt = 0; rt < 2; ++rt)
            acc[rt][tt] = __builtin_amdgcn_mfma_f32_16x16x32_bf16(PJ[rt][tt], bid, acc[rt][tt], 0, 0, 0);

    // ---- GEMM2 through fenced wave-private h chunks; B streamed from L2 ----
    f32x4 acc2[2][8];
    #pragma unroll
    for (int rt = 0; rt < 2; ++rt)
        #pragma unroll
        for (int tt = 0; tt < 8; ++tt) acc2[rt][tt] = (f32x4){0.f, 0.f, 0.f, 0.f};

    #pragma unroll
    for (int q = 0; q < 4; ++q) {
        #pragma unroll
        for (int rt = 0; rt < 2; ++rt)
            #pragma unroll
            for (int t2 = 0; t2 < 2; ++t2) {
                int tt = q * 2 + t2;
                int slot = t2 * 2 + (lr >> 3);
                #pragma unroll
                for (int r = 0; r < 4; r += 2) {
                    int row0 = rt * 16 + kg * 4 + r;
                    float x0 = acc[rt][tt][r] + b1r[tt];
                    float x1 = acc[rt][tt][r + 1] + b1r[tt];
                    float h0 = x0 / (1.0f + __expf(-x0));
                    float h1 = x1 / (1.0f + __expf(-x1));
                    unsigned p = cvt_pk_bf16(h0, h1);
                    int byte0 = row0 * 64 + ((slot ^ ((row0 >> 1) & 3)) << 4) + (lr & 7) * 2;
                    *(unsigned short*)(S + byte0) = (unsigned short)p;
                    *(unsigned short*)(S + byte0 + 64) = (unsigned short)(p >> 16);
                }
            }
        lds_fence();
        bf16x8 A2[2];
        #pragma unroll
        for (int rt = 0; rt < 2; ++rt) {
            int row = rt * 16 + lr;
            int byte = row * 64 + ((kg ^ ((row >> 1) & 3)) << 4);
            A2[rt] = *(const bf16x8*)(S + byte);
        }
        ds_order();
        #pragma unroll
        for (int tt = 0; tt < 8; ++tt) {
            bf16x8 B = *(const bf16x8*)(Wt2e + (tt * 16 + lr) * 128 + q * 32 + kg * 8);
            #pragma unroll
            for (int rt = 0; rt < 2; ++rt)
                acc2[rt][tt] = __builtin_amdgcn_mfma_f32_16x16x32_bf16(A2[rt], B, acc2[rt][tt], 0, 0, 0);
        }
    }

    // ---- epilogue: fenced f32 strips; residual loads batched per strip (L2-hot) ----
    #pragma unroll
    for (int rt = 0; rt < 2; ++rt)
        #pragma unroll
        for (int ch = 0; ch < 2; ++ch) {
            float4 rs4[4];
            #pragma unroll
            for (int i = 0; i < 4; ++i) {
                int row = (l >> 4) + i * 4;
                int slot = l & 15;
                long gidx = (long)(tb + rt * 16 + row) * DIM + ch * 64 + slot * 4;
                rs4[i] = *(const float4*)(edge_feat + gidx);
            }
            #pragma unroll
            for (int t2 = 0; t2 < 4; ++t2) {
                int tt = ch * 4 + t2;
                #pragma unroll
                for (int r = 0; r < 4; ++r) {
                    int row = kg * 4 + r;
                    int col = t2 * 16 + lr;
                    int byte = row * 256 + (((col >> 2) ^ (row & 15)) << 4) + (col & 3) * 4;
                    *(float*)(S + byte) = acc2[rt][tt][r] + b2r[tt];
                }
            }
            lds_fence();
            #pragma unroll
            for (int i = 0; i < 4; ++i) {
                int row = (l >> 4) + i * 4;
                int slot = l & 15;
                int byte = row * 256 + ((slot ^ (row & 15)) << 4);
                float4 v = *(const float4*)(S + byte);
                long gidx = (long)(tb + rt * 16 + row) * DIM + ch * 64 + slot * 4;
                v.x += rs4[i].x; v.y += rs4[i].y; v.z += rs4[i].z; v.w += rs4[i].w;
                *(float4*)(out_edge + gidx) = v;
            }
            ds_order();
        }
}

// ---------------- mean aggregation: 1 node per block, 4 waves (one 8-deep burst each) ----------------
__global__ void agg_kernel(const float* __restrict__ edge_out,
                           const int* __restrict__ offsets, const int* __restrict__ counts,
                           const int* __restrict__ elist,
                           unsigned short* __restrict__ agg_bf) {
    __shared__ float part[4][128];
    int wv = threadIdx.x >> 6;
    int l = threadIdx.x & 63;
    int n = blockIdx.x;
    int off = offsets[n], cnt = counts[n];
    int beg = (cnt * wv) >> 2;
    int end = (cnt * (wv + 1)) >> 2;
    float a0 = 0.f, a1 = 0.f;
    int i = beg;
    for (; i + 8 <= end; i += 8) {
        int ee[8];
        #pragma unroll
        for (int j = 0; j < 8; ++j) ee[j] = elist[off + i + j];
        float2 vv[8];
        #pragma unroll
        for (int j = 0; j < 8; ++j) vv[j] = *(const float2*)(edge_out + (long)ee[j] * DIM + l * 2);
        #pragma unroll
        for (int j = 0; j < 8; ++j) { a0 += vv[j].x; a1 += vv[j].y; }
    }
    for (; i < end; ++i) {
        int e = elist[off + i];
        float2 v = *(const float2*)(edge_out + (long)e * DIM + l * 2);
        a0 += v.x; a1 += v.y;
    }
    part[wv][l * 2] = a0;
    part[wv][l * 2 + 1] = a1;
    __syncthreads();
    if (wv == 0) {
        a0 = part[0][l * 2] + part[1][l * 2] + part[2][l * 2] + part[3][l * 2];
        a1 = part[0][l * 2 + 1] + part[1][l * 2 + 1] + part[2][l * 2 + 1] + part[3][l * 2 + 1];
        float inv = 1.0f / fmaxf((float)cnt, 1.0f);
        *(unsigned*)(agg_bf + (long)n * DIM + l * 2) = cvt_pk_bf16(a0 * inv, a1 * inv);
    }
}

// ---------------- node MLP ----------------
#define SLICE_B 8448
__launch_bounds__(256, 4)
__global__ void node_kernel(const float* __restrict__ node_feat,
                            const unsigned short* __restrict__ node_bf,
                            const unsigned short* __restrict__ agg_bf,
                            const unsigned short* __restrict__ Wt1n,
                            const unsigned short* __restrict__ Wt2n,
                            const float* __restrict__ b1n,
                            const float* __restrict__ b2n,
                            float* __restrict__ out_node) {
    __shared__ char lds[4][SLICE_B];
    const int tid = threadIdx.x;
    const int wv = tid >> 6;
    const int l = tid & 63;
    const int lr = l & 15;
    const int kg = l >> 4;
    char* slice = lds[wv];

    const int nBase = blockIdx.x * 128;
    const int wBase = nBase + wv * 32;

    int rowc[2];
    #pragma unroll
    for (int rt = 0; rt < 2; ++rt) {
        int row = wBase + rt * 16 + lr;
        rowc[rt] = row < N_NODES ? row : N_NODES - 1;
    }

    f32x4 acc[2][8];
    #pragma unroll
    for (int rt = 0; rt < 2; ++rt)
        #pragma unroll
        for (int t = 0; t < 8; ++t) acc[rt][t] = (f32x4){0.f, 0.f, 0.f, 0.f};

    #pragma unroll
    for (int s = 0; s < 8; ++s) {
        const int kk = s * 32 + kg * 8;
        bf16x8 A[2];
        if (s < 4) {
            #pragma unroll
            for (int rt = 0; rt < 2; ++rt)
                A[rt] = *(const bf16x8*)(node_bf + (long)rowc[rt] * DIM + kk);
        } else {
            #pragma unroll
            for (int rt = 0; rt < 2; ++rt)
                A[rt] = *(const bf16x8*)(agg_bf + (long)rowc[rt] * DIM + (kk - 128));
        }
        #pragma unroll
        for (int t = 0; t < 8; ++t) {
            bf16x8 B = *(const bf16x8*)(Wt1n + (t * 16 + lr) * 256 + kk);
            #pragma unroll
            for (int rt = 0; rt < 2; ++rt)
                acc[rt][t] = __builtin_amdgcn_mfma_f32_16x16x32_bf16(A[rt], B, acc[rt][t], 0, 0, 0);
        }
    }

    #pragma unroll
    for (int rt = 0; rt < 2; ++rt) {
        #pragma unroll
        for (int t = 0; t < 8; ++t) {
            float b1 = b1n[t * 16 + lr];
            int col = t * 16 + lr;
            #pragma unroll
            for (int r = 0; r < 4; ++r) {
                int row = rt * 16 + kg * 4 + r;
                float x = acc[rt][t][r] + b1;
                float h = x / (1.0f + __expf(-x));
                int byte = (row * 256 + col * 2) ^ ((row & 7) << 4);
                *(unsigned short*)(slice + byte) = f2bf(h);
            }
        }
    }
    __syncthreads();

    f32x4 acc2[2][8];
    #pragma unroll
    for (int rt = 0; rt < 2; ++rt)
        #pragma unroll
        for (int t = 0; t < 8; ++t) acc2[rt][t] = (f32x4){0.f, 0.f, 0.f, 0.f};

    #pragma unroll
    for (int s = 0; s < 4; ++s) {
        const int kk = s * 32 + kg * 8;
        bf16x8 A[2];
        #pragma unroll
        for (int rt = 0; rt < 2; ++rt) {
            int row = rt * 16 + lr;
            int byte = (row * 256 + kk * 2) ^ ((row & 7) << 4);
            A[rt] = *(const bf16x8*)(slice + byte);
        }
        #pragma unroll
        for (int t = 0; t < 8; ++t) {
            bf16x8 B = *(const bf16x8*)(Wt2n + (t * 16 + lr) * DIM + kk);
            #pragma unroll
            for (int rt = 0; rt < 2; ++rt)
                acc2[rt][t] = __builtin_amdgcn_mfma_f32_16x16x32_bf16(A[rt], B, acc2[rt][t], 0, 0, 0);
        }
    }
    __syncthreads();

    #pragma unroll
    for (int rt = 0; rt < 2; ++rt) {
        float* sf = (float*)slice;
        #pragma unroll
        for (int t = 0; t < 8; ++t) {
            float b2 = b2n[t * 16 + lr];
            int col = t * 16 + lr;
            #pragma unroll
            for (int r = 0; r < 4; ++r) {
                int row = kg * 4 + r;
                int colp = col ^ (row & 12);
                sf[row * 132 + colp] = acc2[rt][t][r] + b2;
            }
        }
        __syncthreads();
        #pragma unroll
        for (int rr = 0; rr < 8; ++rr) {
            int row = rr * 2 + (l >> 5);
            int c4 = (l & 31) * 4;
            int cswz = c4 ^ (row & 12);
            float4 v = *(const float4*)(sf + row * 132 + cswz);
            int grow = wBase + rt * 16 + row;
            if (grow < N_NODES) {
                long gidx = (long)grow * DIM + c4;
                float4 rsd = *(const float4*)(node_feat + gidx);
                v.x += rsd.x; v.y += rsd.y; v.z += rsd.z; v.w += rsd.w;
                *(float4*)(out_node + gidx) = v;
            }
        }
        __syncthreads();
    }
}

extern "C" void kernel_launch(void* const* d_in, const int* in_sizes, int n_in,
                              void* d_out, int out_size, void* d_ws, size_t ws_size,
                              hipStream_t stream) {
    const float* node_feat = (const float*)d_in[0];
    const float* edge_feat = (const float*)d_in[1];
    const int*   eidx      = (const int*)d_in[2];
    const float* W1e = (const float*)d_in[3];
    const float* b1e = (const float*)d_in[4];
    const float* W2e = (const float*)d_in[5];
    const float* b2e = (const float*)d_in[6];
    const float* W1n = (const float*)d_in[7];
    const float* b1n = (const float*)d_in[8];
    const float* W2n = (const float*)d_in[9];
    const float* b2n = (const float*)d_in[10];

    char* ws = (char*)d_ws;
    size_t off = 0;
    auto alloc = [&](size_t bytes) {
        void* p = ws + off;
        off += (bytes + 255) & ~(size_t)255;
        return p;
    };
    unsigned short* node_bf = (unsigned short*)alloc((size_t)N_NODES * DIM * 2);
    unsigned short* agg_bf  = (unsigned short*)alloc((size_t)N_NODES * DIM * 2);
    unsigned short* Ps      = (unsigned short*)alloc((size_t)N_NODES * DIM * 2);
    unsigned short* Pd      = (unsigned short*)alloc((size_t)N_NODES * DIM * 2);
    unsigned short* Wt1ee   = (unsigned short*)alloc((size_t)DIM * DIM * 2);
    unsigned short* Wt1es   = (unsigned short*)alloc((size_t)DIM * DIM * 2);
    unsigned short* Wt1ed   = (unsigned short*)alloc((size_t)DIM * DIM * 2);
    unsigned short* Wt2e    = (unsigned short*)alloc((size_t)DIM * DIM * 2);
    unsigned short* Wt1n    = (unsigned short*)alloc((size_t)DIM * 256 * 2);
    unsigned short* Wt2n    = (unsigned short*)alloc((size_t)DIM * DIM * 2);
    int* counts  = (int*)alloc((size_t)N_NODES * 4);
    int* offsets = (int*)alloc((size_t)N_NODES * 4);
    int* cursor  = (int*)alloc((size_t)N_NODES * 4);
    int* elist   = (int*)alloc((size_t)N_EDGES * 4);

    float* out_node = (float*)d_out;
    float* out_edge = out_node + (size_t)N_NODES * DIM;

    prep_kernel<<<512, 256, 0, stream>>>(node_feat, W1e, W2e, W1n, W2n, node_bf,
                                         Wt1ee, Wt1es, Wt1ed, Wt2e, Wt1n, Wt2n, counts);
    proj_kernel<<<(N_NODES + 127) / 128, 256, 0, stream>>>(node_bf, Wt1es, Wt1ed, Ps, Pd);
    count_kernel<<<(N_EDGES + 255) / 256, 256, 0, stream>>>(eidx, counts);
    scan_kernel<<<1, 1024, 0, stream>>>(counts, offsets, cursor);
    scatter_kernel<<<(N_EDGES + 255) / 256, 256, 0, stream>>>(eidx, cursor, elist);
    edge_kernel<<<N_EDGES / 128, 256, 0, stream>>>(edge_feat, eidx, Ps, Pd, Wt1ee, Wt2e,
                                                   b1e, b2e, out_edge);
    agg_kernel<<<N_NODES, 256, 0, stream>>>(out_edge, offsets, counts, elist, agg_bf);
    node_kernel<<<(N_NODES + 127) / 128, 256, 0, stream>>>(node_feat, node_bf, agg_bf,
                                                           Wt1n, Wt2n, b1n, b2n, out_node);
}

// Round 13
// 437.078 us; speedup vs baseline: 1.3117x; 1.2988x over previous
//
#include <hip/hip_runtime.h>
#include <hip/hip_bf16.h>
#include <stdint.h>

#define N_NODES 20000
#define N_EDGES 640000
#define DIM 128

using bf16x8 = __attribute__((ext_vector_type(8))) short;
using f32x4  = __attribute__((ext_vector_type(4))) float;

static __device__ __forceinline__ unsigned short f2bf(float f) {
    union { float f; unsigned int u; } v; v.f = f;
    unsigned int r = v.u + 0x7FFFu + ((v.u >> 16) & 1u);
    return (unsigned short)(r >> 16);
}

// HW packed f32->bf16 (RNE): dst.lo16 = bf16(a), dst.hi16 = bf16(b). 1 VALU op.
static __device__ __forceinline__ unsigned cvt_pk_bf16(float a, float b) {
    unsigned r;
    asm("v_cvt_pk_bf16_f32 %0, %1, %2" : "=v"(r) : "v"(a), "v"(b));
    return r;
}

static __device__ __forceinline__ void glds16(const unsigned short* g, char* lds) {
    __builtin_amdgcn_global_load_lds(
        (const __attribute__((address_space(1))) unsigned int*)(const void*)g,
        (__attribute__((address_space(3))) unsigned int*)(void*)lds, 16, 0, 0);
}

// LDS write->read fence, wave-local (pins compiler order; HW LDS is in-order per wave).
static __device__ __forceinline__ void lds_fence() {
    __builtin_amdgcn_sched_barrier(0);
    asm volatile("s_waitcnt lgkmcnt(0)" ::: "memory");
    __builtin_amdgcn_sched_barrier(0);
}
// WAR pin: DS ops may not cross (VMEM/VALU/MFMA free to move).
static __device__ __forceinline__ void ds_order() {
    __builtin_amdgcn_sched_barrier(0x7F);
}

// ---------------- prep: bf16 node table, split transposed bf16 weights, edge counting ----------------
// counts[] is zeroed by hipMemsetAsync before this kernel; counting fused here (saves a launch).
__global__ void prep_kernel(const float* __restrict__ node_feat,
                            const int* __restrict__ eidx,
                            const float* __restrict__ W1e, const float* __restrict__ W2e,
                            const float* __restrict__ W1n, const float* __restrict__ W2n,
                            unsigned short* __restrict__ node_bf,
                            unsigned short* __restrict__ Wt1ee, unsigned short* __restrict__ Wt1es,
                            unsigned short* __restrict__ Wt1ed, unsigned short* __restrict__ Wt2e,
                            unsigned short* __restrict__ Wt1n, unsigned short* __restrict__ Wt2n,
                            int* __restrict__ counts) {
    int tid = blockIdx.x * blockDim.x + threadIdx.x;
    int stride = gridDim.x * blockDim.x;
    for (int i = tid; i < N_NODES * DIM / 8; i += stride) {
        const float* p = node_feat + (size_t)i * 8;
        float4 f0 = *(const float4*)p;
        float4 f1 = *(const float4*)(p + 4);
        bf16x8 a;
        unsigned* au = (unsigned*)&a;
        au[0] = cvt_pk_bf16(f0.x, f0.y);
        au[1] = cvt_pk_bf16(f0.z, f0.w);
        au[2] = cvt_pk_bf16(f1.x, f1.y);
        au[3] = cvt_pk_bf16(f1.z, f1.w);
        *(bf16x8*)(node_bf + (size_t)i * 8) = a;
    }
    // W1e is [384][128]; rows 0:128 edge part, 128:256 src part, 256:384 dst part.
    for (int i = tid; i < DIM * DIM; i += stride) {
        int n = i >> 7, k = i & 127;
        Wt1ee[i] = f2bf(W1e[k * DIM + n]);
        Wt1es[i] = f2bf(W1e[(128 + k) * DIM + n]);
        Wt1ed[i] = f2bf(W1e[(256 + k) * DIM + n]);
        Wt2e[i]  = f2bf(W2e[k * DIM + n]);
        Wt2n[i]  = f2bf(W2n[k * DIM + n]);
    }
    for (int i = tid; i < DIM * 256; i += stride) { int n = i / 256, k = i % 256; Wt1n[i] = f2bf(W1n[k * DIM + n]); }
    for (int e = tid; e < N_EDGES; e += stride) atomicAdd(&counts[eidx[N_EDGES + e]], 1);
}

// ---------------- node projections: P = node @ W1e_{s|d}, T split across grid ----------------
// grid = 2 * ceil(N_NODES/128); even blocks -> Ps, odd blocks -> Pd. LDS 66 KB -> 2 blocks/CU.
__launch_bounds__(256, 1)
__global__ void proj_kernel(const unsigned short* __restrict__ node_bf,
                            const unsigned short* __restrict__ Wt1es,
                            const unsigned short* __restrict__ Wt1ed,
                            unsigned short* __restrict__ Ps,
                            unsigned short* __restrict__ Pd) {
    __shared__ char ldsW[32768];
    __shared__ char ldsS[4][8448];
    const int tid = threadIdx.x;
    const int wv = tid >> 6, l = tid & 63, lr = l & 15, kg = l >> 4;
    char* S = ldsS[wv];
    const int T = blockIdx.x & 1;
    const unsigned short* Wsrc = T ? Wt1ed : Wt1es;
    unsigned short* Out = T ? Pd : Ps;
    const int wb = (blockIdx.x >> 1) * 128 + wv * 32;

    int n0 = wb + lr;       if (n0 >= N_NODES) n0 = N_NODES - 1;
    int n1 = wb + 16 + lr;  if (n1 >= N_NODES) n1 = N_NODES - 1;

    bf16x8 A[4][2];
    #pragma unroll
    for (int st = 0; st < 4; ++st) {
        A[st][0] = *(const bf16x8*)(node_bf + (long)n0 * DIM + st * 32 + kg * 8);
        A[st][1] = *(const bf16x8*)(node_bf + (long)n1 * DIM + st * 32 + kg * 8);
    }

    #pragma unroll
    for (int c = 0; c < 8; ++c) {
        int Sc = c * 256 + tid;          // 0..2047
        int n = Sc >> 4, sp = Sc & 15;
        int s = (sp & 8) | ((sp ^ n) & 7);
        glds16(Wsrc + n * 128 + s * 8, ldsW + Sc * 16);
    }
    __syncthreads();

    f32x4 acc[2][8];
    #pragma unroll
    for (int rt = 0; rt < 2; ++rt)
        #pragma unroll
        for (int tt = 0; tt < 8; ++tt) acc[rt][tt] = (f32x4){0.f, 0.f, 0.f, 0.f};
    #pragma unroll
    for (int s = 0; s < 4; ++s) {
        int sl = s * 4 + kg;
        int sp = (sl & 8) | ((sl ^ lr) & 7);
        #pragma unroll
        for (int tt = 0; tt < 8; ++tt) {
            bf16x8 B = *(const bf16x8*)(ldsW + (tt * 16 + lr) * 256 + sp * 16);
            #pragma unroll
            for (int rt = 0; rt < 2; ++rt)
                acc[rt][tt] = __builtin_amdgcn_mfma_f32_16x16x32_bf16(A[s][rt], B, acc[rt][tt], 0, 0, 0);
        }
    }
    float* sf = (float*)S;
    #pragma unroll
    for (int rt = 0; rt < 2; ++rt) {
        #pragma unroll
        for (int tt = 0; tt < 8; ++tt) {
            int col = tt * 16 + lr;
            #pragma unroll
            for (int r = 0; r < 4; ++r) {
                int row = kg * 4 + r;
                sf[row * 132 + (col ^ (row & 12))] = acc[rt][tt][r];
            }
        }
        lds_fence();
        #pragma unroll
        for (int rr = 0; rr < 8; ++rr) {
            int row = rr * 2 + (l >> 5);
            int c4 = (l & 31) * 4;
            float4 v = *(const float4*)(sf + row * 132 + (c4 ^ (row & 12)));
            int nrow = wb + rt * 16 + row;
            if (nrow < N_NODES) {
                uint2 u;
                u.x = cvt_pk_bf16(v.x, v.y);
                u.y = cvt_pk_bf16(v.z, v.w);
                *(uint2*)(Out + (long)nrow * DIM + c4) = u;
            }
        }
        ds_order();
    }
}

// ---------------- CSR build ----------------
__global__ void scan_kernel(const int* __restrict__ counts, int* __restrict__ offsets,
                            int* __restrict__ cursor) {
    __shared__ int wsum[16];
    const int CH = 20;
    int tid = threadIdx.x;
    int lane = tid & 63, wid = tid >> 6;
    int base = tid * CH;
    int s = 0;
    #pragma unroll
    for (int j = 0; j < CH; ++j) { int i = base + j; s += (i < N_NODES) ? counts[i] : 0; }
    int chunk = s;
    #pragma unroll
    for (int off = 1; off < 64; off <<= 1) { int t = __shfl_up(s, off, 64); if (lane >= off) s += t; }
    if (lane == 63) wsum[wid] = s;
    __syncthreads();
    if (tid == 0) {
        int run = 0;
        for (int w = 0; w < 16; ++w) { int t = wsum[w]; wsum[w] = run; run += t; }
    }
    __syncthreads();
    int run = wsum[wid] + s - chunk;
    for (int j = 0; j < CH; ++j) {
        int i = base + j;
        if (i < N_NODES) { offsets[i] = run; cursor[i] = run; run += counts[i]; }
    }
}

__global__ void scatter_kernel(const int* __restrict__ eidx, int* __restrict__ cursor,
                               int* __restrict__ elist) {
    int e = blockIdx.x * blockDim.x + threadIdx.x;
    if (e < N_EDGES) {
        int p = atomicAdd(&cursor[eidx[N_EDGES + e]], 1);
        elist[p] = e;
    }
}

// ---------------- edge MLP: K=128 coalesced GEMM + projection injection (R10 exact) ----------------
// C1 = edge_feat @ W1e_e + Ps[src] + Pd[dst]  (Ps/Pd injected via MFMA with one-hot B).
// Then silu, GEMM2 (W2e), +b2, +residual. Block = 128 edges, 4 waves x 32 rows,
// LDS = 32K+32K+4x4K = 80 KB -> 2 blocks/CU. This exact shape compiles to 124 VGPR,
// no spill; R7/R8/R11/R12 all showed any deviation (more waves/tiles/launch-bounds)
// makes the allocator cap at <=128 and spill. CLOSED — do not touch.
__launch_bounds__(256, 2)
__global__ void edge_kernel(const float* __restrict__ edge_feat,
                            const int* __restrict__ eidx,
                            const unsigned short* __restrict__ Ps,
                            const unsigned short* __restrict__ Pd,
                            const unsigned short* __restrict__ Wt1ee,
                            const unsigned short* __restrict__ Wt2e,
                            const float* __restrict__ b1e,
                            const float* __restrict__ b2e,
                            float* __restrict__ out_edge) {
    __shared__ char ldsW1[32768];
    __shared__ char ldsW2[32768];
    __shared__ char ldsS[4][4096];
    const int tid = threadIdx.x;
    const int wv = tid >> 6, l = tid & 63, lr = l & 15, kg = l >> 4;
    char* S = ldsS[wv];
    const int tb = blockIdx.x * 128 + wv * 32;

    const int e0 = tb + lr, e1 = tb + 16 + lr;
    const int s0 = eidx[e0], d0 = eidx[N_EDGES + e0];
    const int s1 = eidx[e1], d1 = eidx[N_EDGES + e1];

    // ---- issue edge stream loads first (coalesced, also warms L2 for residual) ----
    float4 E[4][2][2];
    #pragma unroll
    for (int st = 0; st < 4; ++st) {
        const float* p0 = edge_feat + (long)e0 * DIM + st * 32 + kg * 8;
        const float* p1 = edge_feat + (long)e1 * DIM + st * 32 + kg * 8;
        E[st][0][0] = *(const float4*)p0; E[st][0][1] = *(const float4*)(p0 + 4);
        E[st][1][0] = *(const float4*)p1; E[st][1][1] = *(const float4*)(p1 + 4);
    }

    // ---- projection gathers in injection-A layout: kg<2 -> Ps[src], kg>=2 -> Pd[dst] ----
    const unsigned short* Tbl = (kg < 2) ? Ps : Pd;
    const long r0 = (long)((kg < 2) ? s0 : d0) * DIM;
    const long r1 = (long)((kg < 2) ? s1 : d1) * DIM;
    const int ko = (kg & 1) * 8;
    bf16x8 PJ[2][8];
    #pragma unroll
    for (int tt = 0; tt < 8; ++tt) {
        PJ[0][tt] = *(const bf16x8*)(Tbl + r0 + tt * 16 + ko);
        PJ[1][tt] = *(const bf16x8*)(Tbl + r1 + tt * 16 + ko);
    }

    float b1r[8], b2r[8];
    #pragma unroll
    for (int tt = 0; tt < 8; ++tt) { b1r[tt] = b1e[tt * 16 + lr]; b2r[tt] = b2e[tt * 16 + lr]; }

    // ---- stage both weight matrices once (linear dest, pre-swizzled source) ----
    #pragma unroll
    for (int c = 0; c < 8; ++c) {
        int Sc = c * 256 + tid;          // 0..2047
        int n = Sc >> 4, sp = Sc & 15;
        int s = (sp & 8) | ((sp ^ n) & 7);
        glds16(Wt1ee + n * 128 + s * 8, ldsW1 + Sc * 16);
        glds16(Wt2e + n * 128 + s * 8, ldsW2 + Sc * 16);
    }
    __syncthreads();

    // ---- one-hot B fragment for the injection MFMA ----
    bf16x8 bid;
    #pragma unroll
    for (int j = 0; j < 8; ++j) {
        int k = kg * 8 + j;
        int kk = (k < 16) ? k : k - 16;
        bid[j] = (short)((kk == lr) ? 0x3F80 : 0);
    }

    // ---- GEMM1: K=128 over edge_feat (converted inline via cvt_pk) ----
    f32x4 acc[2][8];
    #pragma unroll
    for (int rt = 0; rt < 2; ++rt)
        #pragma unroll
        for (int tt = 0; tt < 8; ++tt) acc[rt][tt] = (f32x4){0.f, 0.f, 0.f, 0.f};

    #pragma unroll
    for (int s = 0; s < 4; ++s) {
        bf16x8 EB[2];
        #pragma unroll
        for (int rt = 0; rt < 2; ++rt) {
            bf16x8 a;
            unsigned* au = (unsigned*)&a;
            au[0] = cvt_pk_bf16(E[s][rt][0].x, E[s][rt][0].y);
            au[1] = cvt_pk_bf16(E[s][rt][0].z, E[s][rt][0].w);
            au[2] = cvt_pk_bf16(E[s][rt][1].x, E[s][rt][1].y);
            au[3] = cvt_pk_bf16(E[s][rt][1].z, E[s][rt][1].w);
            EB[rt] = a;
        }
        int sl = s * 4 + kg;
        int sp = (sl & 8) | ((sl ^ lr) & 7);
        #pragma unroll
        for (int tt = 0; tt < 8; ++tt) {
            bf16x8 B = *(const bf16x8*)(ldsW1 + (tt * 16 + lr) * 256 + sp * 16);
            #pragma unroll
            for (int rt = 0; rt < 2; ++rt)
                acc[rt][tt] = __builtin_amdgcn_mfma_f32_16x16x32_bf16(EB[rt], B, acc[rt][tt], 0, 0, 0);
        }
    }
    // ---- inject Ps[src] + Pd[dst] ----
    #pragma unroll
    for (int tt = 0; tt < 8; ++tt)
        #pragma unroll
        for (int rt = 0; rt < 2; ++rt)
            acc[rt][tt] = __builtin_amdgcn_mfma_f32_16x16x32_bf16(PJ[rt][tt], bid, acc[rt][tt], 0, 0, 0);

    // ---- GEMM2 through fenced wave-private h chunks (cvt_pk + hi extract) ----
    f32x4 acc2[2][8];
    #pragma unroll
    for (int rt = 0; rt < 2; ++rt)
        #pragma unroll
        for (int tt = 0; tt < 8; ++tt) acc2[rt][tt] = (f32x4){0.f, 0.f, 0.f, 0.f};

    #pragma unroll
    for (int q = 0; q < 4; ++q) {
        #pragma unroll
        for (int rt = 0; rt < 2; ++rt)
            #pragma unroll
            for (int t2 = 0; t2 < 2; ++t2) {
                int tt = q * 2 + t2;
                int slot = t2 * 2 + (lr >> 3);
                #pragma unroll
                for (int r = 0; r < 4; r += 2) {
                    int row0 = rt * 16 + kg * 4 + r;
                    float x0 = acc[rt][tt][r] + b1r[tt];
                    float x1 = acc[rt][tt][r + 1] + b1r[tt];
                    float h0 = x0 / (1.0f + __expf(-x0));
                    float h1 = x1 / (1.0f + __expf(-x1));
                    unsigned p = cvt_pk_bf16(h0, h1);
                    int byte0 = row0 * 64 + ((slot ^ ((row0 >> 1) & 3)) << 4) + (lr & 7) * 2;
                    *(unsigned short*)(S + byte0) = (unsigned short)p;
                    *(unsigned short*)(S + byte0 + 64) = (unsigned short)(p >> 16);
                }
            }
        lds_fence();
        bf16x8 A2[2];
        #pragma unroll
        for (int rt = 0; rt < 2; ++rt) {
            int row = rt * 16 + lr;
            int byte = row * 64 + ((kg ^ ((row >> 1) & 3)) << 4);
            A2[rt] = *(const bf16x8*)(S + byte);
        }
        ds_order();
        int sl2 = q * 4 + kg;
        int sp2 = (sl2 & 8) | ((sl2 ^ lr) & 7);
        #pragma unroll
        for (int tt = 0; tt < 8; ++tt) {
            bf16x8 B = *(const bf16x8*)(ldsW2 + (tt * 16 + lr) * 256 + sp2 * 16);
            #pragma unroll
            for (int rt = 0; rt < 2; ++rt)
                acc2[rt][tt] = __builtin_amdgcn_mfma_f32_16x16x32_bf16(A2[rt], B, acc2[rt][tt], 0, 0, 0);
        }
    }

    // ---- epilogue: fenced f32 strips; residual loads batched per strip (L2-hot) ----
    #pragma unroll
    for (int rt = 0; rt < 2; ++rt)
        #pragma unroll
        for (int ch = 0; ch < 2; ++ch) {
            float4 rs4[4];
            #pragma unroll
            for (int i = 0; i < 4; ++i) {
                int row = (l >> 4) + i * 4;
                int slot = l & 15;
                long gidx = (long)(tb + rt * 16 + row) * DIM + ch * 64 + slot * 4;
                rs4[i] = *(const float4*)(edge_feat + gidx);
            }
            #pragma unroll
            for (int t2 = 0; t2 < 4; ++t2) {
                int tt = ch * 4 + t2;
                #pragma unroll
                for (int r = 0; r < 4; ++r) {
                    int row = kg * 4 + r;
                    int col = t2 * 16 + lr;
                    int byte = row * 256 + (((col >> 2) ^ (row & 15)) << 4) + (col & 3) * 4;
                    *(float*)(S + byte) = acc2[rt][tt][r] + b2r[tt];
                }
            }
            lds_fence();
            #pragma unroll
            for (int i = 0; i < 4; ++i) {
                int row = (l >> 4) + i * 4;
                int slot = l & 15;
                int byte = row * 256 + ((slot ^ (row & 15)) << 4);
                float4 v = *(const float4*)(S + byte);
                long gidx = (long)(tb + rt * 16 + row) * DIM + ch * 64 + slot * 4;
                v.x += rs4[i].x; v.y += rs4[i].y; v.z += rs4[i].z; v.w += rs4[i].w;
                *(float4*)(out_edge + gidx) = v;
            }
            ds_order();
        }
}

// ---------------- mean aggregation: 1 node per block, 4 waves (one 8-deep burst each) ----------------
__global__ void agg_kernel(const float* __restrict__ edge_out,
                           const int* __restrict__ offsets, const int* __restrict__ counts,
                           const int* __restrict__ elist,
                           unsigned short* __restrict__ agg_bf) {
    __shared__ float part[4][128];
    int wv = threadIdx.x >> 6;
    int l = threadIdx.x & 63;
    int n = blockIdx.x;
    int off = offsets[n], cnt = counts[n];
    int beg = (cnt * wv) >> 2;
    int end = (cnt * (wv + 1)) >> 2;
    float a0 = 0.f, a1 = 0.f;
    int i = beg;
    for (; i + 8 <= end; i += 8) {
        int ee[8];
        #pragma unroll
        for (int j = 0; j < 8; ++j) ee[j] = elist[off + i + j];
        float2 vv[8];
        #pragma unroll
        for (int j = 0; j < 8; ++j) vv[j] = *(const float2*)(edge_out + (long)ee[j] * DIM + l * 2);
        #pragma unroll
        for (int j = 0; j < 8; ++j) { a0 += vv[j].x; a1 += vv[j].y; }
    }
    for (; i < end; ++i) {
        int e = elist[off + i];
        float2 v = *(const float2*)(edge_out + (long)e * DIM + l * 2);
        a0 += v.x; a1 += v.y;
    }
    part[wv][l * 2] = a0;
    part[wv][l * 2 + 1] = a1;
    __syncthreads();
    if (wv == 0) {
        a0 = part[0][l * 2] + part[1][l * 2] + part[2][l * 2] + part[3][l * 2];
        a1 = part[0][l * 2 + 1] + part[1][l * 2 + 1] + part[2][l * 2 + 1] + part[3][l * 2 + 1];
        float inv = 1.0f / fmaxf((float)cnt, 1.0f);
        *(unsigned*)(agg_bf + (long)n * DIM + l * 2) = cvt_pk_bf16(a0 * inv, a1 * inv);
    }
}

// ---------------- node MLP ----------------
#define SLICE_B 8448
__launch_bounds__(256, 4)
__global__ void node_kernel(const float* __restrict__ node_feat,
                            const unsigned short* __restrict__ node_bf,
                            const unsigned short* __restrict__ agg_bf,
                            const unsigned short* __restrict__ Wt1n,
                            const unsigned short* __restrict__ Wt2n,
                            const float* __restrict__ b1n,
                            const float* __restrict__ b2n,
                            float* __restrict__ out_node) {
    __shared__ char lds[4][SLICE_B];
    const int tid = threadIdx.x;
    const int wv = tid >> 6;
    const int l = tid & 63;
    const int lr = l & 15;
    const int kg = l >> 4;
    char* slice = lds[wv];

    const int nBase = blockIdx.x * 128;
    const int wBase = nBase + wv * 32;

    int rowc[2];
    #pragma unroll
    for (int rt = 0; rt < 2; ++rt) {
        int row = wBase + rt * 16 + lr;
        rowc[rt] = row < N_NODES ? row : N_NODES - 1;
    }

    f32x4 acc[2][8];
    #pragma unroll
    for (int rt = 0; rt < 2; ++rt)
        #pragma unroll
        for (int t = 0; t < 8; ++t) acc[rt][t] = (f32x4){0.f, 0.f, 0.f, 0.f};

    #pragma unroll
    for (int s = 0; s < 8; ++s) {
        const int kk = s * 32 + kg * 8;
        bf16x8 A[2];
        if (s < 4) {
            #pragma unroll
            for (int rt = 0; rt < 2; ++rt)
                A[rt] = *(const bf16x8*)(node_bf + (long)rowc[rt] * DIM + kk);
        } else {
            #pragma unroll
            for (int rt = 0; rt < 2; ++rt)
                A[rt] = *(const bf16x8*)(agg_bf + (long)rowc[rt] * DIM + (kk - 128));
        }
        #pragma unroll
        for (int t = 0; t < 8; ++t) {
            bf16x8 B = *(const bf16x8*)(Wt1n + (t * 16 + lr) * 256 + kk);
            #pragma unroll
            for (int rt = 0; rt < 2; ++rt)
                acc[rt][t] = __builtin_amdgcn_mfma_f32_16x16x32_bf16(A[rt], B, acc[rt][t], 0, 0, 0);
        }
    }

    #pragma unroll
    for (int rt = 0; rt < 2; ++rt) {
        #pragma unroll
        for (int t = 0; t < 8; ++t) {
            float b1 = b1n[t * 16 + lr];
            int col = t * 16 + lr;
            #pragma unroll
            for (int r = 0; r < 4; ++r) {
                int row = rt * 16 + kg * 4 + r;
                float x = acc[rt][t][r] + b1;
                float h = x / (1.0f + __expf(-x));
                int byte = (row * 256 + col * 2) ^ ((row & 7) << 4);
                *(unsigned short*)(slice + byte) = f2bf(h);
            }
        }
    }
    __syncthreads();

    f32x4 acc2[2][8];
    #pragma unroll
    for (int rt = 0; rt < 2; ++rt)
        #pragma unroll
        for (int t = 0; t < 8; ++t) acc2[rt][t] = (f32x4){0.f, 0.f, 0.f, 0.f};

    #pragma unroll
    for (int s = 0; s < 4; ++s) {
        const int kk = s * 32 + kg * 8;
        bf16x8 A[2];
        #pragma unroll
        for (int rt = 0; rt < 2; ++rt) {
            int row = rt * 16 + lr;
            int byte = (row * 256 + kk * 2) ^ ((row & 7) << 4);
            A[rt] = *(const bf16x8*)(slice + byte);
        }
        #pragma unroll
        for (int t = 0; t < 8; ++t) {
            bf16x8 B = *(const bf16x8*)(Wt2n + (t * 16 + lr) * DIM + kk);
            #pragma unroll
            for (int rt = 0; rt < 2; ++rt)
                acc2[rt][t] = __builtin_amdgcn_mfma_f32_16x16x32_bf16(A[rt], B, acc2[rt][t], 0, 0, 0);
        }
    }
    __syncthreads();

    #pragma unroll
    for (int rt = 0; rt < 2; ++rt) {
        float* sf = (float*)slice;
        #pragma unroll
        for (int t = 0; t < 8; ++t) {
            float b2 = b2n[t * 16 + lr];
            int col = t * 16 + lr;
            #pragma unroll
            for (int r = 0; r < 4; ++r) {
                int row = kg * 4 + r;
                int colp = col ^ (row & 12);
                sf[row * 132 + colp] = acc2[rt][t][r] + b2;
            }
        }
        __syncthreads();
        #pragma unroll
        for (int rr = 0; rr < 8; ++rr) {
            int row = rr * 2 + (l >> 5);
            int c4 = (l & 31) * 4;
            int cswz = c4 ^ (row & 12);
            float4 v = *(const float4*)(sf + row * 132 + cswz);
            int grow = wBase + rt * 16 + row;
            if (grow < N_NODES) {
                long gidx = (long)grow * DIM + c4;
                float4 rsd = *(const float4*)(node_feat + gidx);
                v.x += rsd.x; v.y += rsd.y; v.z += rsd.z; v.w += rsd.w;
                *(float4*)(out_node + gidx) = v;
            }
        }
        __syncthreads();
    }
}

extern "C" void kernel_launch(void* const* d_in, const int* in_sizes, int n_in,
                              void* d_out, int out_size, void* d_ws, size_t ws_size,
                              hipStream_t stream) {
    const float* node_feat = (const float*)d_in[0];
    const float* edge_feat = (const float*)d_in[1];
    const int*   eidx      = (const int*)d_in[2];
    const float* W1e = (const float*)d_in[3];
    const float* b1e = (const float*)d_in[4];
    const float* W2e = (const float*)d_in[5];
    const float* b2e = (const float*)d_in[6];
    const float* W1n = (const float*)d_in[7];
    const float* b1n = (const float*)d_in[8];
    const float* W2n = (const float*)d_in[9];
    const float* b2n = (const float*)d_in[10];

    char* ws = (char*)d_ws;
    size_t off = 0;
    auto alloc = [&](size_t bytes) {
        void* p = ws + off;
        off += (bytes + 255) & ~(size_t)255;
        return p;
    };
    unsigned short* node_bf = (unsigned short*)alloc((size_t)N_NODES * DIM * 2);
    unsigned short* agg_bf  = (unsigned short*)alloc((size_t)N_NODES * DIM * 2);
    unsigned short* Ps      = (unsigned short*)alloc((size_t)N_NODES * DIM * 2);
    unsigned short* Pd      = (unsigned short*)alloc((size_t)N_NODES * DIM * 2);
    unsigned short* Wt1ee   = (unsigned short*)alloc((size_t)DIM * DIM * 2);
    unsigned short* Wt1es   = (unsigned short*)alloc((size_t)DIM * DIM * 2);
    unsigned short* Wt1ed   = (unsigned short*)alloc((size_t)DIM * DIM * 2);
    unsigned short* Wt2e    = (unsigned short*)alloc((size_t)DIM * DIM * 2);
    unsigned short* Wt1n    = (unsigned short*)alloc((size_t)DIM * 256 * 2);
    unsigned short* Wt2n    = (unsigned short*)alloc((size_t)DIM * DIM * 2);
    int* counts  = (int*)alloc((size_t)N_NODES * 4);
    int* offsets = (int*)alloc((size_t)N_NODES * 4);
    int* cursor  = (int*)alloc((size_t)N_NODES * 4);
    int* elist   = (int*)alloc((size_t)N_EDGES * 4);

    float* out_node = (float*)d_out;
    float* out_edge = out_node + (size_t)N_NODES * DIM;

    hipMemsetAsync(counts, 0, (size_t)N_NODES * 4, stream);
    prep_kernel<<<512, 256, 0, stream>>>(node_feat, eidx, W1e, W2e, W1n, W2n, node_bf,
                                         Wt1ee, Wt1es, Wt1ed, Wt2e, Wt1n, Wt2n, counts);
    proj_kernel<<<2 * ((N_NODES + 127) / 128), 256, 0, stream>>>(node_bf, Wt1es, Wt1ed, Ps, Pd);
    scan_kernel<<<1, 1024, 0, stream>>>(counts, offsets, cursor);
    scatter_kernel<<<(N_EDGES + 255) / 256, 256, 0, stream>>>(eidx, cursor, elist);
    edge_kernel<<<N_EDGES / 128, 256, 0, stream>>>(edge_feat, eidx, Ps, Pd, Wt1ee, Wt2e,
                                                   b1e, b2e, out_edge);
    agg_kernel<<<N_NODES, 256, 0, stream>>>(out_edge, offsets, counts, elist, agg_bf);
    node_kernel<<<(N_NODES + 127) / 128, 256, 0, stream>>>(node_feat, node_bf, agg_bf,
                                                           Wt1n, Wt2n, b1n, b2n, out_node);
}

// Round 14
// 434.690 us; speedup vs baseline: 1.3189x; 1.0055x over previous
//
#include <hip/hip_runtime.h>
#include <hip/hip_bf16.h>
#include <stdint.h>

#define N_NODES 20000
#define N_EDGES 640000
#define DIM 128

using bf16x8 = __attribute__((ext_vector_type(8))) short;
using f32x4  = __attribute__((ext_vector_type(4))) float;

static __device__ __forceinline__ unsigned short f2bf(float f) {
    union { float f; unsigned int u; } v; v.f = f;
    unsigned int r = v.u + 0x7FFFu + ((v.u >> 16) & 1u);
    return (unsigned short)(r >> 16);
}

// HW packed f32->bf16 (RNE): dst.lo16 = bf16(a), dst.hi16 = bf16(b). 1 VALU op.
static __device__ __forceinline__ unsigned cvt_pk_bf16(float a, float b) {
    unsigned r;
    asm("v_cvt_pk_bf16_f32 %0, %1, %2" : "=v"(r) : "v"(a), "v"(b));
    return r;
}

static __device__ __forceinline__ void glds16(const unsigned short* g, char* lds) {
    __builtin_amdgcn_global_load_lds(
        (const __attribute__((address_space(1))) unsigned int*)(const void*)g,
        (__attribute__((address_space(3))) unsigned int*)(void*)lds, 16, 0, 0);
}

// LDS write->read fence, wave-local (pins compiler order; HW LDS is in-order per wave).
static __device__ __forceinline__ void lds_fence() {
    __builtin_amdgcn_sched_barrier(0);
    asm volatile("s_waitcnt lgkmcnt(0)" ::: "memory");
    __builtin_amdgcn_sched_barrier(0);
}
// WAR pin: DS ops may not cross (VMEM/VALU/MFMA free to move).
static __device__ __forceinline__ void ds_order() {
    __builtin_amdgcn_sched_barrier(0x7F);
}

// ---------------- prep: bf16 node table, split transposed bf16 weights, edge counting ----------------
// counts[] is zeroed by hipMemsetAsync before this kernel; counting fused here (saves a launch).
__global__ void prep_kernel(const float* __restrict__ node_feat,
                            const int* __restrict__ eidx,
                            const float* __restrict__ W1e, const float* __restrict__ W2e,
                            const float* __restrict__ W1n, const float* __restrict__ W2n,
                            unsigned short* __restrict__ node_bf,
                            unsigned short* __restrict__ Wt1ee, unsigned short* __restrict__ Wt1es,
                            unsigned short* __restrict__ Wt1ed, unsigned short* __restrict__ Wt2e,
                            unsigned short* __restrict__ Wt1n, unsigned short* __restrict__ Wt2n,
                            int* __restrict__ counts) {
    int tid = blockIdx.x * blockDim.x + threadIdx.x;
    int stride = gridDim.x * blockDim.x;
    for (int i = tid; i < N_NODES * DIM / 8; i += stride) {
        const float* p = node_feat + (size_t)i * 8;
        float4 f0 = *(const float4*)p;
        float4 f1 = *(const float4*)(p + 4);
        bf16x8 a;
        unsigned* au = (unsigned*)&a;
        au[0] = cvt_pk_bf16(f0.x, f0.y);
        au[1] = cvt_pk_bf16(f0.z, f0.w);
        au[2] = cvt_pk_bf16(f1.x, f1.y);
        au[3] = cvt_pk_bf16(f1.z, f1.w);
        *(bf16x8*)(node_bf + (size_t)i * 8) = a;
    }
    // W1e is [384][128]; rows 0:128 edge part, 128:256 src part, 256:384 dst part.
    for (int i = tid; i < DIM * DIM; i += stride) {
        int n = i >> 7, k = i & 127;
        Wt1ee[i] = f2bf(W1e[k * DIM + n]);
        Wt1es[i] = f2bf(W1e[(128 + k) * DIM + n]);
        Wt1ed[i] = f2bf(W1e[(256 + k) * DIM + n]);
        Wt2e[i]  = f2bf(W2e[k * DIM + n]);
        Wt2n[i]  = f2bf(W2n[k * DIM + n]);
    }
    for (int i = tid; i < DIM * 256; i += stride) { int n = i / 256, k = i % 256; Wt1n[i] = f2bf(W1n[k * DIM + n]); }
    for (int e = tid; e < N_EDGES; e += stride) atomicAdd(&counts[eidx[N_EDGES + e]], 1);
}

// ---------------- node projections: P = node @ W1e_{s|d}, T split across grid ----------------
// grid = 2 * ceil(N_NODES/128); even blocks -> Ps, odd blocks -> Pd. LDS 66 KB -> 2 blocks/CU.
__launch_bounds__(256, 1)
__global__ void proj_kernel(const unsigned short* __restrict__ node_bf,
                            const unsigned short* __restrict__ Wt1es,
                            const unsigned short* __restrict__ Wt1ed,
                            unsigned short* __restrict__ Ps,
                            unsigned short* __restrict__ Pd) {
    __shared__ char ldsW[32768];
    __shared__ char ldsS[4][8448];
    const int tid = threadIdx.x;
    const int wv = tid >> 6, l = tid & 63, lr = l & 15, kg = l >> 4;
    char* S = ldsS[wv];
    const int T = blockIdx.x & 1;
    const unsigned short* Wsrc = T ? Wt1ed : Wt1es;
    unsigned short* Out = T ? Pd : Ps;
    const int wb = (blockIdx.x >> 1) * 128 + wv * 32;

    int n0 = wb + lr;       if (n0 >= N_NODES) n0 = N_NODES - 1;
    int n1 = wb + 16 + lr;  if (n1 >= N_NODES) n1 = N_NODES - 1;

    bf16x8 A[4][2];
    #pragma unroll
    for (int st = 0; st < 4; ++st) {
        A[st][0] = *(const bf16x8*)(node_bf + (long)n0 * DIM + st * 32 + kg * 8);
        A[st][1] = *(const bf16x8*)(node_bf + (long)n1 * DIM + st * 32 + kg * 8);
    }

    #pragma unroll
    for (int c = 0; c < 8; ++c) {
        int Sc = c * 256 + tid;          // 0..2047
        int n = Sc >> 4, sp = Sc & 15;
        int s = (sp & 8) | ((sp ^ n) & 7);
        glds16(Wsrc + n * 128 + s * 8, ldsW + Sc * 16);
    }
    __syncthreads();

    f32x4 acc[2][8];
    #pragma unroll
    for (int rt = 0; rt < 2; ++rt)
        #pragma unroll
        for (int tt = 0; tt < 8; ++tt) acc[rt][tt] = (f32x4){0.f, 0.f, 0.f, 0.f};
    #pragma unroll
    for (int s = 0; s < 4; ++s) {
        int sl = s * 4 + kg;
        int sp = (sl & 8) | ((sl ^ lr) & 7);
        #pragma unroll
        for (int tt = 0; tt < 8; ++tt) {
            bf16x8 B = *(const bf16x8*)(ldsW + (tt * 16 + lr) * 256 + sp * 16);
            #pragma unroll
            for (int rt = 0; rt < 2; ++rt)
                acc[rt][tt] = __builtin_amdgcn_mfma_f32_16x16x32_bf16(A[s][rt], B, acc[rt][tt], 0, 0, 0);
        }
    }
    float* sf = (float*)S;
    #pragma unroll
    for (int rt = 0; rt < 2; ++rt) {
        #pragma unroll
        for (int tt = 0; tt < 8; ++tt) {
            int col = tt * 16 + lr;
            #pragma unroll
            for (int r = 0; r < 4; ++r) {
                int row = kg * 4 + r;
                sf[row * 132 + (col ^ (row & 12))] = acc[rt][tt][r];
            }
        }
        lds_fence();
        #pragma unroll
        for (int rr = 0; rr < 8; ++rr) {
            int row = rr * 2 + (l >> 5);
            int c4 = (l & 31) * 4;
            float4 v = *(const float4*)(sf + row * 132 + (c4 ^ (row & 12)));
            int nrow = wb + rt * 16 + row;
            if (nrow < N_NODES) {
                uint2 u;
                u.x = cvt_pk_bf16(v.x, v.y);
                u.y = cvt_pk_bf16(v.z, v.w);
                *(uint2*)(Out + (long)nrow * DIM + c4) = u;
            }
        }
        ds_order();
    }
}

// ---------------- CSR build ----------------
__global__ void scan_kernel(const int* __restrict__ counts, int* __restrict__ offsets,
                            int* __restrict__ cursor) {
    __shared__ int wsum[16];
    const int CH = 20;
    int tid = threadIdx.x;
    int lane = tid & 63, wid = tid >> 6;
    int base = tid * CH;
    int s = 0;
    #pragma unroll
    for (int j = 0; j < CH; ++j) { int i = base + j; s += (i < N_NODES) ? counts[i] : 0; }
    int chunk = s;
    #pragma unroll
    for (int off = 1; off < 64; off <<= 1) { int t = __shfl_up(s, off, 64); if (lane >= off) s += t; }
    if (lane == 63) wsum[wid] = s;
    __syncthreads();
    if (tid == 0) {
        int run = 0;
        for (int w = 0; w < 16; ++w) { int t = wsum[w]; wsum[w] = run; run += t; }
    }
    __syncthreads();
    int run = wsum[wid] + s - chunk;
    for (int j = 0; j < CH; ++j) {
        int i = base + j;
        if (i < N_NODES) { offsets[i] = run; cursor[i] = run; run += counts[i]; }
    }
}

__global__ void scatter_kernel(const int* __restrict__ eidx, int* __restrict__ cursor,
                               int* __restrict__ elist) {
    int e = blockIdx.x * blockDim.x + threadIdx.x;
    if (e < N_EDGES) {
        int p = atomicAdd(&cursor[eidx[N_EDGES + e]], 1);
        elist[p] = e;
    }
}

// ---------------- edge MLP: K=128 coalesced GEMM + projection injection (R10 exact) ----------------
// CLOSED configuration: 124 VGPR, no spill. Do not touch (R7/R8/R11/R12 evidence).
__launch_bounds__(256, 2)
__global__ void edge_kernel(const float* __restrict__ edge_feat,
                            const int* __restrict__ eidx,
                            const unsigned short* __restrict__ Ps,
                            const unsigned short* __restrict__ Pd,
                            const unsigned short* __restrict__ Wt1ee,
                            const unsigned short* __restrict__ Wt2e,
                            const float* __restrict__ b1e,
                            const float* __restrict__ b2e,
                            float* __restrict__ out_edge) {
    __shared__ char ldsW1[32768];
    __shared__ char ldsW2[32768];
    __shared__ char ldsS[4][4096];
    const int tid = threadIdx.x;
    const int wv = tid >> 6, l = tid & 63, lr = l & 15, kg = l >> 4;
    char* S = ldsS[wv];
    const int tb = blockIdx.x * 128 + wv * 32;

    const int e0 = tb + lr, e1 = tb + 16 + lr;
    const int s0 = eidx[e0], d0 = eidx[N_EDGES + e0];
    const int s1 = eidx[e1], d1 = eidx[N_EDGES + e1];

    // ---- issue edge stream loads first (coalesced, also warms L2 for residual) ----
    float4 E[4][2][2];
    #pragma unroll
    for (int st = 0; st < 4; ++st) {
        const float* p0 = edge_feat + (long)e0 * DIM + st * 32 + kg * 8;
        const float* p1 = edge_feat + (long)e1 * DIM + st * 32 + kg * 8;
        E[st][0][0] = *(const float4*)p0; E[st][0][1] = *(const float4*)(p0 + 4);
        E[st][1][0] = *(const float4*)p1; E[st][1][1] = *(const float4*)(p1 + 4);
    }

    // ---- projection gathers in injection-A layout: kg<2 -> Ps[src], kg>=2 -> Pd[dst] ----
    const unsigned short* Tbl = (kg < 2) ? Ps : Pd;
    const long r0 = (long)((kg < 2) ? s0 : d0) * DIM;
    const long r1 = (long)((kg < 2) ? s1 : d1) * DIM;
    const int ko = (kg & 1) * 8;
    bf16x8 PJ[2][8];
    #pragma unroll
    for (int tt = 0; tt < 8; ++tt) {
        PJ[0][tt] = *(const bf16x8*)(Tbl + r0 + tt * 16 + ko);
        PJ[1][tt] = *(const bf16x8*)(Tbl + r1 + tt * 16 + ko);
    }

    float b1r[8], b2r[8];
    #pragma unroll
    for (int tt = 0; tt < 8; ++tt) { b1r[tt] = b1e[tt * 16 + lr]; b2r[tt] = b2e[tt * 16 + lr]; }

    // ---- stage both weight matrices once (linear dest, pre-swizzled source) ----
    #pragma unroll
    for (int c = 0; c < 8; ++c) {
        int Sc = c * 256 + tid;          // 0..2047
        int n = Sc >> 4, sp = Sc & 15;
        int s = (sp & 8) | ((sp ^ n) & 7);
        glds16(Wt1ee + n * 128 + s * 8, ldsW1 + Sc * 16);
        glds16(Wt2e + n * 128 + s * 8, ldsW2 + Sc * 16);
    }
    __syncthreads();

    // ---- one-hot B fragment for the injection MFMA ----
    bf16x8 bid;
    #pragma unroll
    for (int j = 0; j < 8; ++j) {
        int k = kg * 8 + j;
        int kk = (k < 16) ? k : k - 16;
        bid[j] = (short)((kk == lr) ? 0x3F80 : 0);
    }

    // ---- GEMM1: K=128 over edge_feat (converted inline via cvt_pk) ----
    f32x4 acc[2][8];
    #pragma unroll
    for (int rt = 0; rt < 2; ++rt)
        #pragma unroll
        for (int tt = 0; tt < 8; ++tt) acc[rt][tt] = (f32x4){0.f, 0.f, 0.f, 0.f};

    #pragma unroll
    for (int s = 0; s < 4; ++s) {
        bf16x8 EB[2];
        #pragma unroll
        for (int rt = 0; rt < 2; ++rt) {
            bf16x8 a;
            unsigned* au = (unsigned*)&a;
            au[0] = cvt_pk_bf16(E[s][rt][0].x, E[s][rt][0].y);
            au[1] = cvt_pk_bf16(E[s][rt][0].z, E[s][rt][0].w);
            au[2] = cvt_pk_bf16(E[s][rt][1].x, E[s][rt][1].y);
            au[3] = cvt_pk_bf16(E[s][rt][1].z, E[s][rt][1].w);
            EB[rt] = a;
        }
        int sl = s * 4 + kg;
        int sp = (sl & 8) | ((sl ^ lr) & 7);
        #pragma unroll
        for (int tt = 0; tt < 8; ++tt) {
            bf16x8 B = *(const bf16x8*)(ldsW1 + (tt * 16 + lr) * 256 + sp * 16);
            #pragma unroll
            for (int rt = 0; rt < 2; ++rt)
                acc[rt][tt] = __builtin_amdgcn_mfma_f32_16x16x32_bf16(EB[rt], B, acc[rt][tt], 0, 0, 0);
        }
    }
    // ---- inject Ps[src] + Pd[dst] ----
    #pragma unroll
    for (int tt = 0; tt < 8; ++tt)
        #pragma unroll
        for (int rt = 0; rt < 2; ++rt)
            acc[rt][tt] = __builtin_amdgcn_mfma_f32_16x16x32_bf16(PJ[rt][tt], bid, acc[rt][tt], 0, 0, 0);

    // ---- GEMM2 through fenced wave-private h chunks (cvt_pk + hi extract) ----
    f32x4 acc2[2][8];
    #pragma unroll
    for (int rt = 0; rt < 2; ++rt)
        #pragma unroll
        for (int tt = 0; tt < 8; ++tt) acc2[rt][tt] = (f32x4){0.f, 0.f, 0.f, 0.f};

    #pragma unroll
    for (int q = 0; q < 4; ++q) {
        #pragma unroll
        for (int rt = 0; rt < 2; ++rt)
            #pragma unroll
            for (int t2 = 0; t2 < 2; ++t2) {
                int tt = q * 2 + t2;
                int slot = t2 * 2 + (lr >> 3);
                #pragma unroll
                for (int r = 0; r < 4; r += 2) {
                    int row0 = rt * 16 + kg * 4 + r;
                    float x0 = acc[rt][tt][r] + b1r[tt];
                    float x1 = acc[rt][tt][r + 1] + b1r[tt];
                    float h0 = x0 / (1.0f + __expf(-x0));
                    float h1 = x1 / (1.0f + __expf(-x1));
                    unsigned p = cvt_pk_bf16(h0, h1);
                    int byte0 = row0 * 64 + ((slot ^ ((row0 >> 1) & 3)) << 4) + (lr & 7) * 2;
                    *(unsigned short*)(S + byte0) = (unsigned short)p;
                    *(unsigned short*)(S + byte0 + 64) = (unsigned short)(p >> 16);
                }
            }
        lds_fence();
        bf16x8 A2[2];
        #pragma unroll
        for (int rt = 0; rt < 2; ++rt) {
            int row = rt * 16 + lr;
            int byte = row * 64 + ((kg ^ ((row >> 1) & 3)) << 4);
            A2[rt] = *(const bf16x8*)(S + byte);
        }
        ds_order();
        int sl2 = q * 4 + kg;
        int sp2 = (sl2 & 8) | ((sl2 ^ lr) & 7);
        #pragma unroll
        for (int tt = 0; tt < 8; ++tt) {
            bf16x8 B = *(const bf16x8*)(ldsW2 + (tt * 16 + lr) * 256 + sp2 * 16);
            #pragma unroll
            for (int rt = 0; rt < 2; ++rt)
                acc2[rt][tt] = __builtin_amdgcn_mfma_f32_16x16x32_bf16(A2[rt], B, acc2[rt][tt], 0, 0, 0);
        }
    }

    // ---- epilogue: fenced f32 strips; residual loads batched per strip (L2-hot) ----
    #pragma unroll
    for (int rt = 0; rt < 2; ++rt)
        #pragma unroll
        for (int ch = 0; ch < 2; ++ch) {
            float4 rs4[4];
            #pragma unroll
            for (int i = 0; i < 4; ++i) {
                int row = (l >> 4) + i * 4;
                int slot = l & 15;
                long gidx = (long)(tb + rt * 16 + row) * DIM + ch * 64 + slot * 4;
                rs4[i] = *(const float4*)(edge_feat + gidx);
            }
            #pragma unroll
            for (int t2 = 0; t2 < 4; ++t2) {
                int tt = ch * 4 + t2;
                #pragma unroll
                for (int r = 0; r < 4; ++r) {
                    int row = kg * 4 + r;
                    int col = t2 * 16 + lr;
                    int byte = row * 256 + (((col >> 2) ^ (row & 15)) << 4) + (col & 3) * 4;
                    *(float*)(S + byte) = acc2[rt][tt][r] + b2r[tt];
                }
            }
            lds_fence();
            #pragma unroll
            for (int i = 0; i < 4; ++i) {
                int row = (l >> 4) + i * 4;
                int slot = l & 15;
                int byte = row * 256 + ((slot ^ (row & 15)) << 4);
                float4 v = *(const float4*)(S + byte);
                long gidx = (long)(tb + rt * 16 + row) * DIM + ch * 64 + slot * 4;
                v.x += rs4[i].x; v.y += rs4[i].y; v.z += rs4[i].z; v.w += rs4[i].w;
                *(float4*)(out_edge + gidx) = v;
            }
            ds_order();
        }
}

// ---------------- mean aggregation: 1 node per block, 4 waves (one 8-deep burst each) ----------------
__global__ void agg_kernel(const float* __restrict__ edge_out,
                           const int* __restrict__ offsets, const int* __restrict__ counts,
                           const int* __restrict__ elist,
                           unsigned short* __restrict__ agg_bf) {
    __shared__ float part[4][128];
    int wv = threadIdx.x >> 6;
    int l = threadIdx.x & 63;
    int n = blockIdx.x;
    int off = offsets[n], cnt = counts[n];
    int beg = (cnt * wv) >> 2;
    int end = (cnt * (wv + 1)) >> 2;
    float a0 = 0.f, a1 = 0.f;
    int i = beg;
    for (; i + 8 <= end; i += 8) {
        int ee[8];
        #pragma unroll
        for (int j = 0; j < 8; ++j) ee[j] = elist[off + i + j];
        float2 vv[8];
        #pragma unroll
        for (int j = 0; j < 8; ++j) vv[j] = *(const float2*)(edge_out + (long)ee[j] * DIM + l * 2);
        #pragma unroll
        for (int j = 0; j < 8; ++j) { a0 += vv[j].x; a1 += vv[j].y; }
    }
    for (; i < end; ++i) {
        int e = elist[off + i];
        float2 v = *(const float2*)(edge_out + (long)e * DIM + l * 2);
        a0 += v.x; a1 += v.y;
    }
    part[wv][l * 2] = a0;
    part[wv][l * 2 + 1] = a1;
    __syncthreads();
    if (wv == 0) {
        a0 = part[0][l * 2] + part[1][l * 2] + part[2][l * 2] + part[3][l * 2];
        a1 = part[0][l * 2 + 1] + part[1][l * 2 + 1] + part[2][l * 2 + 1] + part[3][l * 2 + 1];
        float inv = 1.0f / fmaxf((float)cnt, 1.0f);
        *(unsigned*)(agg_bf + (long)n * DIM + l * 2) = cvt_pk_bf16(a0 * inv, a1 * inv);
    }
}

// ---------------- node MLP: 1-wave blocks, 32 nodes each (grid 625 — 4x parallelism vs 157) ----------------
#define SLICE_B 8448
__launch_bounds__(64, 4)
__global__ void node_kernel(const float* __restrict__ node_feat,
                            const unsigned short* __restrict__ node_bf,
                            const unsigned short* __restrict__ agg_bf,
                            const unsigned short* __restrict__ Wt1n,
                            const unsigned short* __restrict__ Wt2n,
                            const float* __restrict__ b1n,
                            const float* __restrict__ b2n,
                            float* __restrict__ out_node) {
    __shared__ char lds[SLICE_B];
    const int tid = threadIdx.x;
    const int l = tid & 63;
    const int lr = l & 15;
    const int kg = l >> 4;
    char* slice = lds;

    const int wBase = blockIdx.x * 32;

    int rowc[2];
    #pragma unroll
    for (int rt = 0; rt < 2; ++rt) {
        int row = wBase + rt * 16 + lr;
        rowc[rt] = row < N_NODES ? row : N_NODES - 1;
    }

    f32x4 acc[2][8];
    #pragma unroll
    for (int rt = 0; rt < 2; ++rt)
        #pragma unroll
        for (int t = 0; t < 8; ++t) acc[rt][t] = (f32x4){0.f, 0.f, 0.f, 0.f};

    #pragma unroll
    for (int s = 0; s < 8; ++s) {
        const int kk = s * 32 + kg * 8;
        bf16x8 A[2];
        if (s < 4) {
            #pragma unroll
            for (int rt = 0; rt < 2; ++rt)
                A[rt] = *(const bf16x8*)(node_bf + (long)rowc[rt] * DIM + kk);
        } else {
            #pragma unroll
            for (int rt = 0; rt < 2; ++rt)
                A[rt] = *(const bf16x8*)(agg_bf + (long)rowc[rt] * DIM + (kk - 128));
        }
        #pragma unroll
        for (int t = 0; t < 8; ++t) {
            bf16x8 B = *(const bf16x8*)(Wt1n + (t * 16 + lr) * 256 + kk);
            #pragma unroll
            for (int rt = 0; rt < 2; ++rt)
                acc[rt][t] = __builtin_amdgcn_mfma_f32_16x16x32_bf16(A[rt], B, acc[rt][t], 0, 0, 0);
        }
    }

    #pragma unroll
    for (int rt = 0; rt < 2; ++rt) {
        #pragma unroll
        for (int t = 0; t < 8; ++t) {
            float b1 = b1n[t * 16 + lr];
            int col = t * 16 + lr;
            #pragma unroll
            for (int r = 0; r < 4; ++r) {
                int row = rt * 16 + kg * 4 + r;
                float x = acc[rt][t][r] + b1;
                float h = x / (1.0f + __expf(-x));
                int byte = (row * 256 + col * 2) ^ ((row & 7) << 4);
                *(unsigned short*)(slice + byte) = f2bf(h);
            }
        }
    }
    lds_fence();

    f32x4 acc2[2][8];
    #pragma unroll
    for (int rt = 0; rt < 2; ++rt)
        #pragma unroll
        for (int t = 0; t < 8; ++t) acc2[rt][t] = (f32x4){0.f, 0.f, 0.f, 0.f};

    #pragma unroll
    for (int s = 0; s < 4; ++s) {
        const int kk = s * 32 + kg * 8;
        bf16x8 A[2];
        #pragma unroll
        for (int rt = 0; rt < 2; ++rt) {
            int row = rt * 16 + lr;
            int byte = (row * 256 + kk * 2) ^ ((row & 7) << 4);
            A[rt] = *(const bf16x8*)(slice + byte);
        }
        #pragma unroll
        for (int t = 0; t < 8; ++t) {
            bf16x8 B = *(const bf16x8*)(Wt2n + (t * 16 + lr) * DIM + kk);
            #pragma unroll
            for (int rt = 0; rt < 2; ++rt)
                acc2[rt][t] = __builtin_amdgcn_mfma_f32_16x16x32_bf16(A[rt], B, acc2[rt][t], 0, 0, 0);
        }
    }
    ds_order();

    #pragma unroll
    for (int rt = 0; rt < 2; ++rt) {
        float* sf = (float*)slice;
        #pragma unroll
        for (int t = 0; t < 8; ++t) {
            float b2 = b2n[t * 16 + lr];
            int col = t * 16 + lr;
            #pragma unroll
            for (int r = 0; r < 4; ++r) {
                int row = kg * 4 + r;
                int colp = col ^ (row & 12);
                sf[row * 132 + colp] = acc2[rt][t][r] + b2;
            }
        }
        lds_fence();
        #pragma unroll
        for (int rr = 0; rr < 8; ++rr) {
            int row = rr * 2 + (l >> 5);
            int c4 = (l & 31) * 4;
            int cswz = c4 ^ (row & 12);
            float4 v = *(const float4*)(sf + row * 132 + cswz);
            int grow = wBase + rt * 16 + row;
            if (grow < N_NODES) {
                long gidx = (long)grow * DIM + c4;
                float4 rsd = *(const float4*)(node_feat + gidx);
                v.x += rsd.x; v.y += rsd.y; v.z += rsd.z; v.w += rsd.w;
                *(float4*)(out_node + gidx) = v;
            }
        }
        ds_order();
    }
}

extern "C" void kernel_launch(void* const* d_in, const int* in_sizes, int n_in,
                              void* d_out, int out_size, void* d_ws, size_t ws_size,
                              hipStream_t stream) {
    const float* node_feat = (const float*)d_in[0];
    const float* edge_feat = (const float*)d_in[1];
    const int*   eidx      = (const int*)d_in[2];
    const float* W1e = (const float*)d_in[3];
    const float* b1e = (const float*)d_in[4];
    const float* W2e = (const float*)d_in[5];
    const float* b2e = (const float*)d_in[6];
    const float* W1n = (const float*)d_in[7];
    const float* b1n = (const float*)d_in[8];
    const float* W2n = (const float*)d_in[9];
    const float* b2n = (const float*)d_in[10];

    char* ws = (char*)d_ws;
    size_t off = 0;
    auto alloc = [&](size_t bytes) {
        void* p = ws + off;
        off += (bytes + 255) & ~(size_t)255;
        return p;
    };
    unsigned short* node_bf = (unsigned short*)alloc((size_t)N_NODES * DIM * 2);
    unsigned short* agg_bf  = (unsigned short*)alloc((size_t)N_NODES * DIM * 2);
    unsigned short* Ps      = (unsigned short*)alloc((size_t)N_NODES * DIM * 2);
    unsigned short* Pd      = (unsigned short*)alloc((size_t)N_NODES * DIM * 2);
    unsigned short* Wt1ee   = (unsigned short*)alloc((size_t)DIM * DIM * 2);
    unsigned short* Wt1es   = (unsigned short*)alloc((size_t)DIM * DIM * 2);
    unsigned short* Wt1ed   = (unsigned short*)alloc((size_t)DIM * DIM * 2);
    unsigned short* Wt2e    = (unsigned short*)alloc((size_t)DIM * DIM * 2);
    unsigned short* Wt1n    = (unsigned short*)alloc((size_t)DIM * 256 * 2);
    unsigned short* Wt2n    = (unsigned short*)alloc((size_t)DIM * DIM * 2);
    int* counts  = (int*)alloc((size_t)N_NODES * 4);
    int* offsets = (int*)alloc((size_t)N_NODES * 4);
    int* cursor  = (int*)alloc((size_t)N_NODES * 4);
    int* elist   = (int*)alloc((size_t)N_EDGES * 4);

    float* out_node = (float*)d_out;
    float* out_edge = out_node + (size_t)N_NODES * DIM;

    hipMemsetAsync(counts, 0, (size_t)N_NODES * 4, stream);
    prep_kernel<<<512, 256, 0, stream>>>(node_feat, eidx, W1e, W2e, W1n, W2n, node_bf,
                                         Wt1ee, Wt1es, Wt1ed, Wt2e, Wt1n, Wt2n, counts);
    proj_kernel<<<2 * ((N_NODES + 127) / 128), 256, 0, stream>>>(node_bf, Wt1es, Wt1ed, Ps, Pd);
    scan_kernel<<<1, 1024, 0, stream>>>(counts, offsets, cursor);
    scatter_kernel<<<(N_EDGES + 255) / 256, 256, 0, stream>>>(eidx, cursor, elist);
    edge_kernel<<<N_EDGES / 128, 256, 0, stream>>>(edge_feat, eidx, Ps, Pd, Wt1ee, Wt2e,
                                                   b1e, b2e, out_edge);
    agg_kernel<<<N_NODES, 256, 0, stream>>>(out_edge, offsets, counts, elist, agg_bf);
    node_kernel<<<(N_NODES + 31) / 32, 64, 0, stream>>>(node_feat, node_bf, agg_bf,
                                                        Wt1n, Wt2n, b1n, b2n, out_node);
}